// Round 5
// baseline (1710.433 us; speedup 1.0000x reference)
//
#include <hip/hip_runtime.h>
#include <stdint.h>

typedef unsigned short u16;
typedef __attribute__((ext_vector_type(8))) short short8;
typedef __attribute__((ext_vector_type(4))) short s16x4;
typedef __attribute__((ext_vector_type(4))) float f32x4;

struct P4 { float* p[4]; };

#define DEV __device__ __forceinline__

DEV u16 f2bf(float f) {
  union { float f; uint32_t u; } c; c.f = f;
  uint32_t u = c.u;
  uint32_t r = u + 0x7fffu + ((u >> 16) & 1u);  // RNE
  return (u16)(r >> 16);
}

DEV void g2l16(const void* g, void* l) {
  __builtin_amdgcn_global_load_lds((__attribute__((address_space(1))) void*)(g),
                                   (__attribute__((address_space(3))) void*)(l),
                                   16, 0, 0);
}

// ---------------- positional embedding (PositionEmbeddingSine) ----------------
__global__ void pos_kernel(float* __restrict__ pos) {
  int n = blockIdx.x;
  float yv = (float)((n >> 5) + 1) / (32.0f + 1e-6f) * 6.283185307179586f;
  float xv = (float)((n & 31) + 1) / (32.0f + 1e-6f) * 6.283185307179586f;
#pragma unroll
  for (int i = 0; i < 3; i++) {
    int d = threadIdx.x + i * 256;
    int dd = (d < 384) ? d : d - 384;
    float base = (d < 384) ? yv : xv;
    float ex = (float)(dd & ~1) / 384.0f;     // 2*floor(dd/2)/384
    float arg = base / powf(10000.0f, ex);
    pos[(size_t)n * 768 + d] = (dd & 1) ? cosf(arg) : sinf(arg);
  }
}

// ---------------- conv_w fp32 [768][256] -> bf16 (already N x K) ----------------
__global__ void convw_kernel(const float* __restrict__ src, u16* __restrict__ dst) {
  int i = blockIdx.x * 256 + threadIdx.x;
  dst[i] = f2bf(src[i]);
}

// ---------------- 32x32 tile transpose fp32 -> bf16 ----------------
DEV void tile_tr32(const float* __restrict__ src, u16* __restrict__ dst,
                   int R, int C, int tr, int tc, float (*tile)[33]) {
  int tx = threadIdx.x & 31, ty = threadIdx.x >> 5;  // 32 x 8
#pragma unroll
  for (int i = 0; i < 32; i += 8)
    tile[ty + i][tx] = src[(size_t)(tr * 32 + ty + i) * C + tc * 32 + tx];
  __syncthreads();
#pragma unroll
  for (int i = 0; i < 32; i += 8)
    dst[(size_t)(tc * 32 + ty + i) * R + tr * 32 + tx] = f2bf(tile[tx][ty + i]);
}

// all four weights of one layer, transposed to [N][K] bf16, one launch
__global__ void wconv_kernel(const float* __restrict__ qkv_w, const float* __restrict__ out_w,
                             const float* __restrict__ m1w, const float* __restrict__ m2w,
                             u16* __restrict__ wqkv, u16* __restrict__ wout,
                             u16* __restrict__ wm1, u16* __restrict__ wm2, int layer) {
  __shared__ float tile[32][33];
  int tid = blockIdx.x;
  if (tid < 1728) {                                   // qkv_w: [768][2304] -> [2304][768]
    tile_tr32(qkv_w + (size_t)layer * 768 * 2304, wqkv, 768, 2304, tid / 72, tid % 72, tile);
  } else if (tid < 2304) {                            // out_w: [768][768]
    int t2 = tid - 1728;
    tile_tr32(out_w + (size_t)layer * 768 * 768, wout, 768, 768, t2 / 24, t2 % 24, tile);
  } else if (tid < 4608) {                            // mlp_w1: [768][3072] -> [3072][768]
    int t3 = tid - 2304;
    tile_tr32(m1w + (size_t)layer * 768 * 3072, wm1, 768, 3072, t3 / 96, t3 % 96, tile);
  } else {                                            // mlp_w2: [3072][768] -> [768][3072]
    int t4 = tid - 4608;
    tile_tr32(m2w + (size_t)layer * 3072 * 768, wm2, 3072, 768, t4 / 24, t4 % 24, tile);
  }
}

// c_f [B][256][1024] fp32 -> aconv [B][1024][256] bf16
__global__ void cf_tr_kernel(const float* __restrict__ c_f, u16* __restrict__ aconv) {
  __shared__ float tile[32][33];
  int b = blockIdx.z;
  tile_tr32(c_f + (size_t)b * 256 * 1024, aconv + (size_t)b * 1024 * 256,
            256, 1024, blockIdx.y, blockIdx.x, tile);
}

// x [B][1024][768] fp32 -> out [B][768][1024] fp32
__global__ void out_tr_kernel(const float* __restrict__ x, float* __restrict__ out) {
  __shared__ float tile[32][33];
  int b = blockIdx.z;
  const float* src = x + (size_t)b * 1024 * 768;
  float* dst = out + (size_t)b * 768 * 1024;
  int tr = blockIdx.y, tc = blockIdx.x;  // tr over n (32 tiles), tc over d (24 tiles)
  int tx = threadIdx.x & 31, ty = threadIdx.x >> 5;
#pragma unroll
  for (int i = 0; i < 32; i += 8)
    tile[ty + i][tx] = src[(size_t)(tr * 32 + ty + i) * 768 + tc * 32 + tx];
  __syncthreads();
#pragma unroll
  for (int i = 0; i < 32; i += 8)
    dst[(size_t)(tc * 32 + ty + i) * 1024 + tr * 32 + tx] = tile[tx][ty + i];
}

// ---------------- LayerNorm: fp32 in -> bf16 out ----------------
__global__ __launch_bounds__(256) void ln_kernel(const float* __restrict__ x,
                                                 const float* __restrict__ w,
                                                 const float* __restrict__ bsh,
                                                 u16* __restrict__ y) {
  int row = blockIdx.x, t = threadIdx.x;
  const float* xr = x + (size_t)row * 768;
  float v[3], s = 0.f, sq = 0.f;
#pragma unroll
  for (int i = 0; i < 3; i++) { v[i] = xr[t + i * 256]; s += v[i]; sq += v[i] * v[i]; }
#pragma unroll
  for (int off = 32; off; off >>= 1) { s += __shfl_xor(s, off); sq += __shfl_xor(sq, off); }
  __shared__ float ss[4], ssq[4];
  if ((t & 63) == 0) { ss[t >> 6] = s; ssq[t >> 6] = sq; }
  __syncthreads();
  s = ss[0] + ss[1] + ss[2] + ss[3];
  sq = ssq[0] + ssq[1] + ssq[2] + ssq[3];
  float mean = s * (1.0f / 768.0f);
  float var = sq * (1.0f / 768.0f) - mean * mean;
  float rs = rsqrtf(var + 1e-5f);
#pragma unroll
  for (int i = 0; i < 3; i++) {
    int c = t + i * 256;
    y[(size_t)row * 768 + c] = f2bf((v[i] - mean) * rs * w[c] + bsh[c]);
  }
}

// ---------------- fused split-K reduce (+ bias + residual) and LayerNorm ----------------
template <int S, bool DO_LN>
__global__ __launch_bounds__(256) void redln_kernel(P4 parts, const float* __restrict__ xin,
                                                    const float* __restrict__ bias,
                                                    const float* __restrict__ w,
                                                    const float* __restrict__ bsh,
                                                    float* __restrict__ xout,
                                                    u16* __restrict__ y) {
  int row = blockIdx.x, t = threadIdx.x;
  size_t base = (size_t)row * 768;
  float v[3], s = 0.f, sq = 0.f;
#pragma unroll
  for (int i = 0; i < 3; i++) {
    int c = t + i * 256;
    float acc = xin[base + c] + bias[c];
#pragma unroll
    for (int j = 0; j < S; j++) acc += parts.p[j][base + c];
    v[i] = acc;
    xout[base + c] = acc;
    s += acc; sq += acc * acc;
  }
  if constexpr (DO_LN) {
#pragma unroll
    for (int off = 32; off; off >>= 1) { s += __shfl_xor(s, off); sq += __shfl_xor(sq, off); }
    __shared__ float ss[4], ssq[4];
    if ((t & 63) == 0) { ss[t >> 6] = s; ssq[t >> 6] = sq; }
    __syncthreads();
    s = ss[0] + ss[1] + ss[2] + ss[3];
    sq = ssq[0] + ssq[1] + ssq[2] + ssq[3];
    float mean = s * (1.0f / 768.0f);
    float var = sq * (1.0f / 768.0f) - mean * mean;
    float rs = rsqrtf(var + 1e-5f);
#pragma unroll
    for (int i = 0; i < 3; i++) {
      int c = t + i * 256;
      y[base + c] = f2bf((v[i] - mean) * rs * w[c] + bsh[c]);
    }
  }
}

// ---------------- GEMM: C[M,N] = A[M,K](bf16) @ BT[N,K](bf16)^T, epilogues ----------------
constexpr int EPI_BF16 = 0, EPI_BIAS_RES = 1, EPI_BIAS_GELU = 2, EPI_BIAS_POS = 3, EPI_PART = 4;

template <int EPI>
__global__ __launch_bounds__(256, 2) void gemm_bt(
    const u16* __restrict__ A, const u16* __restrict__ BT,
    const float* __restrict__ bias, const float* __restrict__ res,
    void* __restrict__ Cout, int M, int N, int K, P4 parts) {
  __shared__ __align__(16) u16 As[128 * 32];
  __shared__ __align__(16) u16 Bs[128 * 32];
  const int t = threadIdx.x;
  const int w = t >> 6, l = t & 63, lr = l & 15, quad = l >> 4;
  const int bm = blockIdx.y * 128, bn = blockIdx.x * 128;
  const int wm = (w & 1) * 64, wn = (w >> 1) * 64;
  f32x4 acc[4][4];
#pragma unroll
  for (int i = 0; i < 4; i++)
#pragma unroll
    for (int j = 0; j < 4; j++) acc[i][j] = (f32x4){0.f, 0.f, 0.f, 0.f};
  const int c0 = t, c1 = 256 + t;
  const size_t a0 = (size_t)(bm + (c0 >> 2)) * K + (c0 & 3) * 8;
  const size_t a1 = (size_t)(bm + (c1 >> 2)) * K + (c1 & 3) * 8;
  const size_t b0 = (size_t)(bn + (c0 >> 2)) * K + (c0 & 3) * 8;
  const size_t b1 = (size_t)(bn + (c1 >> 2)) * K + (c1 & 3) * 8;
  const int kc = K / (int)gridDim.z;                // K-chunk for split-K (kc==K if z==1)
  const int kBeg = (int)blockIdx.z * kc;
  for (int k0 = kBeg; k0 < kBeg + kc; k0 += 32) {
    g2l16(A + a0 + k0, As + c0 * 8);
    g2l16(A + a1 + k0, As + c1 * 8);
    g2l16(BT + b0 + k0, Bs + c0 * 8);
    g2l16(BT + b1 + k0, Bs + c1 * 8);
    __syncthreads();
    short8 af[4], bf[4];
#pragma unroll
    for (int mi = 0; mi < 4; mi++) af[mi] = *(const short8*)(As + (wm + mi * 16 + lr) * 32 + quad * 8);
#pragma unroll
    for (int nj = 0; nj < 4; nj++) bf[nj] = *(const short8*)(Bs + (wn + nj * 16 + lr) * 32 + quad * 8);
#pragma unroll
    for (int mi = 0; mi < 4; mi++)
#pragma unroll
      for (int nj = 0; nj < 4; nj++)
        acc[mi][nj] = __builtin_amdgcn_mfma_f32_16x16x32_bf16(af[mi], bf[nj], acc[mi][nj], 0, 0, 0);
    __syncthreads();
  }
  float* Pc = (EPI == EPI_PART) ? parts.p[blockIdx.z] : nullptr;
#pragma unroll
  for (int mi = 0; mi < 4; mi++) {
    const int rowb = bm + wm + mi * 16 + quad * 4;
#pragma unroll
    for (int nj = 0; nj < 4; nj++) {
      const int gn = bn + wn + nj * 16 + lr;
#pragma unroll
      for (int r = 0; r < 4; r++) {
        const size_t idx = (size_t)(rowb + r) * N + gn;
        float v = acc[mi][nj][r];
        if constexpr (EPI == EPI_BF16) {
          ((u16*)Cout)[idx] = f2bf(v);
        } else if constexpr (EPI == EPI_BIAS_RES) {
          ((float*)Cout)[idx] = v + bias[gn] + res[idx];
        } else if constexpr (EPI == EPI_BIAS_GELU) {
          float xg = v + bias[gn];
          ((u16*)Cout)[idx] = f2bf(0.5f * xg * (1.0f + erff(xg * 0.70710678118f)));
        } else if constexpr (EPI == EPI_BIAS_POS) {  // conv epilogue, N==768
          ((float*)Cout)[idx] = v + bias[gn] + res[(size_t)((rowb + r) & 1023) * N + gn];
        } else {  // EPI_PART: fp32 partial, combined later by redln_kernel
          Pc[idx] = v;
        }
      }
    }
  }
}

// ---------------- V transpose: qkvb v-cols [4096][2304] -> vT [48][64][1024] ----------------
__global__ __launch_bounds__(256) void vtr_kernel(const u16* __restrict__ qkvb,
                                                  u16* __restrict__ vT) {
  __shared__ uint32_t tile[64][65];
  const int t = threadIdx.x;
  const int bh = blockIdx.y, b = bh / 12, h = bh % 12;
  const int tok0 = blockIdx.x * 64;
  {
    int trow = t >> 2, dc = (t & 3) * 16;
    const u16* src = qkvb + (size_t)(b * 1024 + tok0 + trow) * 2304 + 1536 + h * 64 + dc;
    short8 v0 = *(const short8*)src;
    short8 v1 = *(const short8*)(src + 8);
#pragma unroll
    for (int j = 0; j < 8; j++) {
      tile[trow][dc + j] = (uint32_t)(u16)v0[j];
      tile[trow][dc + 8 + j] = (uint32_t)(u16)v1[j];
    }
  }
  __syncthreads();
  {
    int d = t >> 2, tc = (t & 3) * 16;
    short8 o0, o1;
#pragma unroll
    for (int j = 0; j < 8; j++) {
      o0[j] = (short)(u16)tile[tc + j][d];
      o1[j] = (short)(u16)tile[tc + 8 + j][d];
    }
    u16* dst = vT + (size_t)(bh * 64 + d) * 1024 + tok0 + tc;
    *(short8*)dst = o0;
    *(short8*)(dst + 8) = o1;
  }
}

// ---------------- flash attention, S^T formulation, v2 ----------------
// (unchanged from R4 — verified: 4 waves, double-buffer, swizzled K/V)
__global__ __launch_bounds__(256, 3) void attn_kernel(const u16* __restrict__ qkv,
                                                      const u16* __restrict__ vT,
                                                      u16* __restrict__ o) {
  __shared__ __align__(16) u16 Ks[2][2 * 64 * 32];   // [buf][ks][key][32]
  __shared__ __align__(16) u16 Vs[2][2 * 64 * 32];   // [buf][ks][d][32]
  __shared__ __align__(16) u16 Ps[4][16 * 72];       // per-wave P [qlocal][key], pad 72
  const int t = threadIdx.x;
  const int w = t >> 6, l = t & 63, lr = l & 15, quad = l >> 4;
  const int bh = blockIdx.y, b = bh / 12, h = bh % 12;
  const int qb = blockIdx.x * 64 + w * 16;           // 16 q-rows per wave
  const int swz = (lr >> 1) & 3;                     // read-side column xor

  short8 aq[2];
#pragma unroll
  for (int ks = 0; ks < 2; ks++)
    aq[ks] = *(const short8*)(qkv + (size_t)(b * 1024 + qb + lr) * 2304 +
                              h * 64 + ks * 32 + quad * 8);

  const u16* kbase = qkv + (size_t)(b * 1024) * 2304 + 768 + h * 64;
  const u16* vbase = vT + (size_t)(bh * 64) * 1024;
  u16* Pw = Ps[w];

  f32x4 accO[4];
  float l_loc = 0.f;
#pragma unroll
  for (int dj = 0; dj < 4; dj++) accO[dj] = (f32x4){0.f, 0.f, 0.f, 0.f};

  auto stage = [&](int buf, int kb) {
#pragma unroll
    for (int pass = 0; pass < 2; pass++) {
      int u = pass * 256 + t;                  // 16B unit, 0..511
      int ks = u >> 8, row = (u >> 2) & 63, c4 = u & 3;
      int cs = c4 ^ ((row >> 1) & 3);          // pre-swizzled source column
      g2l16(kbase + (size_t)(kb + row) * 2304 + ks * 32 + cs * 8, Ks[buf] + (size_t)u * 8);
      g2l16(vbase + (size_t)row * 1024 + kb + ks * 32 + cs * 8, Vs[buf] + (size_t)u * 8);
    }
  };

  stage(0, 0);
  __syncthreads();
  int cur = 0;
  for (int kb = 0; kb < 1024; kb += 64) {
    if (kb + 64 < 1024) stage(cur ^ 1, kb + 64);   // prefetch next tile

    f32x4 s[4];
#pragma unroll
    for (int nj = 0; nj < 4; nj++) s[nj] = (f32x4){0.f, 0.f, 0.f, 0.f};
#pragma unroll
    for (int ks = 0; ks < 2; ks++)
#pragma unroll
      for (int nj = 0; nj < 4; nj++) {
        short8 ak = *(const short8*)(Ks[cur] + ks * 2048 + (nj * 16 + lr) * 32 + (quad ^ swz) * 8);
        s[nj] = __builtin_amdgcn_mfma_f32_16x16x32_bf16(ak, aq[ks], s[nj], 0, 0, 0);
      }

    {
      const int rowoff = lr * 72;
#pragma unroll
      for (int nj = 0; nj < 4; nj++) {
        s16x4 pk;
#pragma unroll
        for (int r = 0; r < 4; r++) {
          float p = exp2f(s[nj][r] * 0.18033688011112042f);
          l_loc += p;
          pk[r] = (short)f2bf(p);
        }
        *(s16x4*)(Pw + rowoff + nj * 16 + quad * 4) = pk;
      }
    }

#pragma unroll
    for (int ks = 0; ks < 2; ks++) {
      short8 bp = *(const short8*)(Pw + lr * 72 + ks * 32 + quad * 8);
#pragma unroll
      for (int dj = 0; dj < 4; dj++) {
        short8 av = *(const short8*)(Vs[cur] + ks * 2048 + (dj * 16 + lr) * 32 + (quad ^ swz) * 8);
        accO[dj] = __builtin_amdgcn_mfma_f32_16x16x32_bf16(av, bp, accO[dj], 0, 0, 0);
      }
    }
    __syncthreads();
    cur ^= 1;
  }

  l_loc += __shfl_xor(l_loc, 16);
  l_loc += __shfl_xor(l_loc, 32);
  {
    float inv = 1.0f / l_loc;
    size_t grow = (size_t)(b * 1024 + qb + lr);
#pragma unroll
    for (int dj = 0; dj < 4; dj++) {
      s16x4 ov;
#pragma unroll
      for (int r = 0; r < 4; r++) ov[r] = (short)f2bf(accO[dj][r] * inv);
      *(s16x4*)(o + grow * 768 + h * 64 + dj * 16 + quad * 4) = ov;
    }
  }
}

// ---------------- driver ----------------
extern "C" void kernel_launch(void* const* d_in, const int* in_sizes, int n_in,
                              void* d_out, int out_size, void* d_ws, size_t ws_size,
                              hipStream_t stream) {
  (void)in_sizes; (void)n_in; (void)out_size;
  const float* c_f    = (const float*)d_in[0];
  const float* conv_w = (const float*)d_in[1];
  const float* conv_b = (const float*)d_in[2];
  const float* ln1_w  = (const float*)d_in[3];
  const float* ln1_b  = (const float*)d_in[4];
  const float* qkv_w  = (const float*)d_in[5];
  const float* out_w  = (const float*)d_in[6];
  const float* out_b  = (const float*)d_in[7];
  const float* ln2_w  = (const float*)d_in[8];
  const float* ln2_b  = (const float*)d_in[9];
  const float* m1w    = (const float*)d_in[10];
  const float* m1b    = (const float*)d_in[11];
  const float* m2w    = (const float*)d_in[12];
  const float* m2b    = (const float*)d_in[13];
  float* out = (float*)d_out;

  // Memory plan (sizes are 256-aligned by construction):
  //   pos 3.15M | x 12.58M | y 6.29M | qkvb 18.87M | ob 6.29M | hb 25.17M |
  //   aconv 2.10M | convw 0.39M | [pad 0.66M] | wqkv 3.54M | wout 1.18M |
  //   wm1 4.72M | wm2 4.72M
  // mlp2 split-K=4 partials (12.58M each), live mlp2(l) -> redln-ln1(l+1):
  //   p0 = qkvb[0..), p1 = qkvb[12.58M..)+ob   (qkvb/ob dead after attn/out-proj)
  //   p2 = d_out                                (scratch until final out_tr)
  //   p3 = aconv+convw+pad+wqkv+wout+wm1        (weights dead; redln runs BEFORE
  //        wconv of the next layer, so partial reads precede weight rewrites)
  const size_t PSZ = 4096ull * 768 * 4;                 // 12,582,912
  const size_t BASE = 88997888ull;                      // sum of all non-pad allocs
  const size_t PADB = 655360ull;                        // pad to make p3 exactly PSZ
  const bool big = ws_size >= BASE + PADB;

  char* p = (char*)d_ws;
  auto alloc = [&](size_t bytes) { char* q = p; p += (bytes + 255) & ~(size_t)255; return q; };
  float* pos  = (float*)alloc(1024ull * 768 * 4);
  float* x    = (float*)alloc(4096ull * 768 * 4);
  u16* y      = (u16*)alloc(4096ull * 768 * 2);
  u16* qkvb   = (u16*)alloc(4096ull * 2304 * 2);
  u16* ob     = (u16*)alloc(4096ull * 768 * 2);
  u16* hb     = (u16*)alloc(4096ull * 3072 * 2);
  u16* aconv  = (u16*)alloc(4096ull * 256 * 2);
  u16* convw  = (u16*)alloc(768ull * 256 * 2);
  if (big) alloc(PADB);                                 // pad between convw and wqkv
  u16* wqkv   = (u16*)alloc(2304ull * 768 * 2);
  u16* wout   = (u16*)alloc(768ull * 768 * 2);
  u16* wm1    = (u16*)alloc(3072ull * 768 * 2);
  u16* wm2    = (u16*)alloc(768ull * 3072 * 2);
  // vT [48][64][1024] bf16 (6.3 MB) aliases hb (25 MB): hb dead during attn.
  u16* vT = hb;

  P4 parts{};
  parts.p[0] = (float*)qkvb;
  parts.p[1] = (float*)((char*)qkvb + PSZ);
  int SPLIT = 2;
  if (big) {
    parts.p[2] = (float*)out;       // d_out is scratch until out_tr
    parts.p[3] = (float*)aconv;     // aconv..wm1 contiguous (incl. pad) = PSZ
    SPLIT = 4;
  }
  P4 none{};

  pos_kernel<<<1024, 256, 0, stream>>>(pos);
  convw_kernel<<<768, 256, 0, stream>>>(conv_w, convw);
  cf_tr_kernel<<<dim3(32, 8, 4), 256, 0, stream>>>(c_f, aconv);
  gemm_bt<EPI_BIAS_POS><<<dim3(6, 32), 256, 0, stream>>>(aconv, convw, conv_b, pos, x, 4096, 768, 256, none);

  for (int lyr = 0; lyr < 8; lyr++) {
    // redln FIRST (reads mlp2 partials incl. the weight region), THEN wconv
    if (lyr == 0) {
      ln_kernel<<<4096, 256, 0, stream>>>(x, ln1_w, ln1_b, y);
    } else if (SPLIT == 4) {
      redln_kernel<4, true><<<4096, 256, 0, stream>>>(parts, x, m2b + (lyr - 1) * 768,
                                                      ln1_w + lyr * 768, ln1_b + lyr * 768, x, y);
    } else {
      redln_kernel<2, true><<<4096, 256, 0, stream>>>(parts, x, m2b + (lyr - 1) * 768,
                                                      ln1_w + lyr * 768, ln1_b + lyr * 768, x, y);
    }
    wconv_kernel<<<6912, 256, 0, stream>>>(qkv_w, out_w, m1w, m2w, wqkv, wout, wm1, wm2, lyr);
    gemm_bt<EPI_BF16><<<dim3(18, 32), 256, 0, stream>>>(y, wqkv, nullptr, nullptr, qkvb, 4096, 2304, 768, none);
    vtr_kernel<<<dim3(16, 48), 256, 0, stream>>>(qkvb, vT);
    attn_kernel<<<dim3(16, 48), 256, 0, stream>>>(qkvb, vT, ob);
    gemm_bt<EPI_BIAS_RES><<<dim3(6, 32), 256, 0, stream>>>(ob, wout, out_b + lyr * 768, x, x, 4096, 768, 768, none);
    ln_kernel<<<4096, 256, 0, stream>>>(x, ln2_w + lyr * 768, ln2_b + lyr * 768, y);
    gemm_bt<EPI_BIAS_GELU><<<dim3(24, 32), 256, 0, stream>>>(y, wm1, m1b + lyr * 3072, nullptr, hb, 4096, 3072, 768, none);
    // mlp2: split-K into fp32 partials (768 blocks at SPLIT=4 -> 3 blocks/CU)
    gemm_bt<EPI_PART><<<dim3(6, 32, SPLIT), 256, 0, stream>>>(hb, wm2, nullptr, nullptr, nullptr, 4096, 768, 3072, parts);
  }
  // final combine (no LN needed; consumer is the output transpose)
  if (SPLIT == 4) {
    redln_kernel<4, false><<<4096, 256, 0, stream>>>(parts, x, m2b + 7 * 768, nullptr, nullptr, x, nullptr);
  } else {
    redln_kernel<2, false><<<4096, 256, 0, stream>>>(parts, x, m2b + 7 * 768, nullptr, nullptr, x, nullptr);
  }
  out_tr_kernel<<<dim3(24, 32, 4), 256, 0, stream>>>(x, out);
}

// Round 6
// 1688.474 us; speedup vs baseline: 1.0130x; 1.0130x over previous
//
#include <hip/hip_runtime.h>
#include <stdint.h>

typedef unsigned short u16;
typedef __attribute__((ext_vector_type(8))) short short8;
typedef __attribute__((ext_vector_type(4))) short s16x4;
typedef __attribute__((ext_vector_type(4))) float f32x4;

struct P4 { float* p[4]; };

#define DEV __device__ __forceinline__

DEV u16 f2bf(float f) {
  union { float f; uint32_t u; } c; c.f = f;
  uint32_t u = c.u;
  uint32_t r = u + 0x7fffu + ((u >> 16) & 1u);  // RNE
  return (u16)(r >> 16);
}

DEV void g2l16(const void* g, void* l) {
  __builtin_amdgcn_global_load_lds((__attribute__((address_space(1))) void*)(g),
                                   (__attribute__((address_space(3))) void*)(l),
                                   16, 0, 0);
}

// ---------------- positional embedding (PositionEmbeddingSine) ----------------
__global__ void pos_kernel(float* __restrict__ pos) {
  int n = blockIdx.x;
  float yv = (float)((n >> 5) + 1) / (32.0f + 1e-6f) * 6.283185307179586f;
  float xv = (float)((n & 31) + 1) / (32.0f + 1e-6f) * 6.283185307179586f;
#pragma unroll
  for (int i = 0; i < 3; i++) {
    int d = threadIdx.x + i * 256;
    int dd = (d < 384) ? d : d - 384;
    float base = (d < 384) ? yv : xv;
    float ex = (float)(dd & ~1) / 384.0f;     // 2*floor(dd/2)/384
    float arg = base / powf(10000.0f, ex);
    pos[(size_t)n * 768 + d] = (dd & 1) ? cosf(arg) : sinf(arg);
  }
}

// ---------------- conv_w fp32 [768][256] -> bf16 (already N x K) ----------------
__global__ void convw_kernel(const float* __restrict__ src, u16* __restrict__ dst) {
  int i = blockIdx.x * 256 + threadIdx.x;
  dst[i] = f2bf(src[i]);
}

// ---------------- 32x32 tile transpose fp32 -> bf16 ----------------
DEV void tile_tr32(const float* __restrict__ src, u16* __restrict__ dst,
                   int R, int C, int tr, int tc, float (*tile)[33]) {
  int tx = threadIdx.x & 31, ty = threadIdx.x >> 5;  // 32 x 8
#pragma unroll
  for (int i = 0; i < 32; i += 8)
    tile[ty + i][tx] = src[(size_t)(tr * 32 + ty + i) * C + tc * 32 + tx];
  __syncthreads();
#pragma unroll
  for (int i = 0; i < 32; i += 8)
    dst[(size_t)(tc * 32 + ty + i) * R + tr * 32 + tx] = f2bf(tile[tx][ty + i]);
}

// all four weights of one layer, transposed to [N][K] bf16, one launch
__global__ void wconv_kernel(const float* __restrict__ qkv_w, const float* __restrict__ out_w,
                             const float* __restrict__ m1w, const float* __restrict__ m2w,
                             u16* __restrict__ wqkv, u16* __restrict__ wout,
                             u16* __restrict__ wm1, u16* __restrict__ wm2, int layer) {
  __shared__ float tile[32][33];
  int tid = blockIdx.x;
  if (tid < 1728) {                                   // qkv_w: [768][2304] -> [2304][768]
    tile_tr32(qkv_w + (size_t)layer * 768 * 2304, wqkv, 768, 2304, tid / 72, tid % 72, tile);
  } else if (tid < 2304) {                            // out_w: [768][768]
    int t2 = tid - 1728;
    tile_tr32(out_w + (size_t)layer * 768 * 768, wout, 768, 768, t2 / 24, t2 % 24, tile);
  } else if (tid < 4608) {                            // mlp_w1: [768][3072] -> [3072][768]
    int t3 = tid - 2304;
    tile_tr32(m1w + (size_t)layer * 768 * 3072, wm1, 768, 3072, t3 / 96, t3 % 96, tile);
  } else {                                            // mlp_w2: [3072][768] -> [768][3072]
    int t4 = tid - 4608;
    tile_tr32(m2w + (size_t)layer * 3072 * 768, wm2, 3072, 768, t4 / 24, t4 % 24, tile);
  }
}

// c_f [B][256][1024] fp32 -> aconv [B][1024][256] bf16
__global__ void cf_tr_kernel(const float* __restrict__ c_f, u16* __restrict__ aconv) {
  __shared__ float tile[32][33];
  int b = blockIdx.z;
  tile_tr32(c_f + (size_t)b * 256 * 1024, aconv + (size_t)b * 1024 * 256,
            256, 1024, blockIdx.y, blockIdx.x, tile);
}

// x [B][1024][768] fp32 -> out [B][768][1024] fp32
__global__ void out_tr_kernel(const float* __restrict__ x, float* __restrict__ out) {
  __shared__ float tile[32][33];
  int b = blockIdx.z;
  const float* src = x + (size_t)b * 1024 * 768;
  float* dst = out + (size_t)b * 768 * 1024;
  int tr = blockIdx.y, tc = blockIdx.x;  // tr over n (32 tiles), tc over d (24 tiles)
  int tx = threadIdx.x & 31, ty = threadIdx.x >> 5;
#pragma unroll
  for (int i = 0; i < 32; i += 8)
    tile[ty + i][tx] = src[(size_t)(tr * 32 + ty + i) * 768 + tc * 32 + tx];
  __syncthreads();
#pragma unroll
  for (int i = 0; i < 32; i += 8)
    dst[(size_t)(tc * 32 + ty + i) * 1024 + tr * 32 + tx] = tile[tx][ty + i];
}

// ---------------- LayerNorm: fp32 in -> bf16 out ----------------
__global__ __launch_bounds__(256) void ln_kernel(const float* __restrict__ x,
                                                 const float* __restrict__ w,
                                                 const float* __restrict__ bsh,
                                                 u16* __restrict__ y) {
  int row = blockIdx.x, t = threadIdx.x;
  const float* xr = x + (size_t)row * 768;
  float v[3], s = 0.f, sq = 0.f;
#pragma unroll
  for (int i = 0; i < 3; i++) { v[i] = xr[t + i * 256]; s += v[i]; sq += v[i] * v[i]; }
#pragma unroll
  for (int off = 32; off; off >>= 1) { s += __shfl_xor(s, off); sq += __shfl_xor(sq, off); }
  __shared__ float ss[4], ssq[4];
  if ((t & 63) == 0) { ss[t >> 6] = s; ssq[t >> 6] = sq; }
  __syncthreads();
  s = ss[0] + ss[1] + ss[2] + ss[3];
  sq = ssq[0] + ssq[1] + ssq[2] + ssq[3];
  float mean = s * (1.0f / 768.0f);
  float var = sq * (1.0f / 768.0f) - mean * mean;
  float rs = rsqrtf(var + 1e-5f);
#pragma unroll
  for (int i = 0; i < 3; i++) {
    int c = t + i * 256;
    y[(size_t)row * 768 + c] = f2bf((v[i] - mean) * rs * w[c] + bsh[c]);
  }
}

// ---------------- fused split-K reduce (+ bias + residual) and LayerNorm ----------------
template <int S, bool DO_LN>
__global__ __launch_bounds__(256) void redln_kernel(P4 parts, const float* __restrict__ xin,
                                                    const float* __restrict__ bias,
                                                    const float* __restrict__ w,
                                                    const float* __restrict__ bsh,
                                                    float* __restrict__ xout,
                                                    u16* __restrict__ y) {
  int row = blockIdx.x, t = threadIdx.x;
  size_t base = (size_t)row * 768;
  float v[3], s = 0.f, sq = 0.f;
#pragma unroll
  for (int i = 0; i < 3; i++) {
    int c = t + i * 256;
    float acc = xin[base + c] + bias[c];
#pragma unroll
    for (int j = 0; j < S; j++) acc += parts.p[j][base + c];
    v[i] = acc;
    xout[base + c] = acc;
    s += acc; sq += acc * acc;
  }
  if constexpr (DO_LN) {
#pragma unroll
    for (int off = 32; off; off >>= 1) { s += __shfl_xor(s, off); sq += __shfl_xor(sq, off); }
    __shared__ float ss[4], ssq[4];
    if ((t & 63) == 0) { ss[t >> 6] = s; ssq[t >> 6] = sq; }
    __syncthreads();
    s = ss[0] + ss[1] + ss[2] + ss[3];
    sq = ssq[0] + ssq[1] + ssq[2] + ssq[3];
    float mean = s * (1.0f / 768.0f);
    float var = sq * (1.0f / 768.0f) - mean * mean;
    float rs = rsqrtf(var + 1e-5f);
#pragma unroll
    for (int i = 0; i < 3; i++) {
      int c = t + i * 256;
      y[base + c] = f2bf((v[i] - mean) * rs * w[c] + bsh[c]);
    }
  }
}

// ---------------- GEMM: C[M,N] = A[M,K](bf16) @ BT[N,K](bf16)^T, epilogues ----------------
constexpr int EPI_BF16 = 0, EPI_BIAS_RES = 1, EPI_BIAS_GELU = 2, EPI_BIAS_POS = 3, EPI_PART = 4;

template <int EPI>
__global__ __launch_bounds__(256, 2) void gemm_bt(
    const u16* __restrict__ A, const u16* __restrict__ BT,
    const float* __restrict__ bias, const float* __restrict__ res,
    void* __restrict__ Cout, int M, int N, int K, P4 parts) {
  __shared__ __align__(16) u16 As[128 * 32];
  __shared__ __align__(16) u16 Bs[128 * 32];
  const int t = threadIdx.x;
  const int w = t >> 6, l = t & 63, lr = l & 15, quad = l >> 4;
  const int bm = blockIdx.y * 128, bn = blockIdx.x * 128;
  const int wm = (w & 1) * 64, wn = (w >> 1) * 64;
  f32x4 acc[4][4];
#pragma unroll
  for (int i = 0; i < 4; i++)
#pragma unroll
    for (int j = 0; j < 4; j++) acc[i][j] = (f32x4){0.f, 0.f, 0.f, 0.f};
  const int c0 = t, c1 = 256 + t;
  const size_t a0 = (size_t)(bm + (c0 >> 2)) * K + (c0 & 3) * 8;
  const size_t a1 = (size_t)(bm + (c1 >> 2)) * K + (c1 & 3) * 8;
  const size_t b0 = (size_t)(bn + (c0 >> 2)) * K + (c0 & 3) * 8;
  const size_t b1 = (size_t)(bn + (c1 >> 2)) * K + (c1 & 3) * 8;
  const int kc = K / (int)gridDim.z;                // K-chunk for split-K (kc==K if z==1)
  const int kBeg = (int)blockIdx.z * kc;
  for (int k0 = kBeg; k0 < kBeg + kc; k0 += 32) {
    g2l16(A + a0 + k0, As + c0 * 8);
    g2l16(A + a1 + k0, As + c1 * 8);
    g2l16(BT + b0 + k0, Bs + c0 * 8);
    g2l16(BT + b1 + k0, Bs + c1 * 8);
    __syncthreads();
    short8 af[4], bf[4];
#pragma unroll
    for (int mi = 0; mi < 4; mi++) af[mi] = *(const short8*)(As + (wm + mi * 16 + lr) * 32 + quad * 8);
#pragma unroll
    for (int nj = 0; nj < 4; nj++) bf[nj] = *(const short8*)(Bs + (wn + nj * 16 + lr) * 32 + quad * 8);
#pragma unroll
    for (int mi = 0; mi < 4; mi++)
#pragma unroll
      for (int nj = 0; nj < 4; nj++)
        acc[mi][nj] = __builtin_amdgcn_mfma_f32_16x16x32_bf16(af[mi], bf[nj], acc[mi][nj], 0, 0, 0);
    __syncthreads();
  }
  float* Pc = (EPI == EPI_PART) ? parts.p[blockIdx.z] : nullptr;
#pragma unroll
  for (int mi = 0; mi < 4; mi++) {
    const int rowb = bm + wm + mi * 16 + quad * 4;
#pragma unroll
    for (int nj = 0; nj < 4; nj++) {
      const int gn = bn + wn + nj * 16 + lr;
#pragma unroll
      for (int r = 0; r < 4; r++) {
        const size_t idx = (size_t)(rowb + r) * N + gn;
        float v = acc[mi][nj][r];
        if constexpr (EPI == EPI_BF16) {
          ((u16*)Cout)[idx] = f2bf(v);
        } else if constexpr (EPI == EPI_BIAS_RES) {
          ((float*)Cout)[idx] = v + bias[gn] + res[idx];
        } else if constexpr (EPI == EPI_BIAS_GELU) {
          float xg = v + bias[gn];
          ((u16*)Cout)[idx] = f2bf(0.5f * xg * (1.0f + erff(xg * 0.70710678118f)));
        } else if constexpr (EPI == EPI_BIAS_POS) {  // conv epilogue, N==768
          ((float*)Cout)[idx] = v + bias[gn] + res[(size_t)((rowb + r) & 1023) * N + gn];
        } else {  // EPI_PART: fp32 partial, combined later by redln_kernel
          Pc[idx] = v;
        }
      }
    }
  }
}

// ---------------- V transpose: qkvb v-cols [4096][2304] -> vT [48][64][1024] ----------------
__global__ __launch_bounds__(256) void vtr_kernel(const u16* __restrict__ qkvb,
                                                  u16* __restrict__ vT) {
  __shared__ uint32_t tile[64][65];
  const int t = threadIdx.x;
  const int bh = blockIdx.y, b = bh / 12, h = bh % 12;
  const int tok0 = blockIdx.x * 64;
  {
    int trow = t >> 2, dc = (t & 3) * 16;
    const u16* src = qkvb + (size_t)(b * 1024 + tok0 + trow) * 2304 + 1536 + h * 64 + dc;
    short8 v0 = *(const short8*)src;
    short8 v1 = *(const short8*)(src + 8);
#pragma unroll
    for (int j = 0; j < 8; j++) {
      tile[trow][dc + j] = (uint32_t)(u16)v0[j];
      tile[trow][dc + 8 + j] = (uint32_t)(u16)v1[j];
    }
  }
  __syncthreads();
  {
    int d = t >> 2, tc = (t & 3) * 16;
    short8 o0, o1;
#pragma unroll
    for (int j = 0; j < 8; j++) {
      o0[j] = (short)(u16)tile[tc + j][d];
      o1[j] = (short)(u16)tile[tc + 8 + j][d];
    }
    u16* dst = vT + (size_t)(bh * 64 + d) * 1024 + tok0 + tc;
    *(short8*)dst = o0;
    *(short8*)(dst + 8) = o1;
  }
}

// ---------------- flash attention, S^T formulation, v2 ----------------
// (unchanged from R4 — verified: 4 waves, double-buffer, swizzled K/V)
__global__ __launch_bounds__(256, 3) void attn_kernel(const u16* __restrict__ qkv,
                                                      const u16* __restrict__ vT,
                                                      u16* __restrict__ o) {
  __shared__ __align__(16) u16 Ks[2][2 * 64 * 32];   // [buf][ks][key][32]
  __shared__ __align__(16) u16 Vs[2][2 * 64 * 32];   // [buf][ks][d][32]
  __shared__ __align__(16) u16 Ps[4][16 * 72];       // per-wave P [qlocal][key], pad 72
  const int t = threadIdx.x;
  const int w = t >> 6, l = t & 63, lr = l & 15, quad = l >> 4;
  const int bh = blockIdx.y, b = bh / 12, h = bh % 12;
  const int qb = blockIdx.x * 64 + w * 16;           // 16 q-rows per wave
  const int swz = (lr >> 1) & 3;                     // read-side column xor

  short8 aq[2];
#pragma unroll
  for (int ks = 0; ks < 2; ks++)
    aq[ks] = *(const short8*)(qkv + (size_t)(b * 1024 + qb + lr) * 2304 +
                              h * 64 + ks * 32 + quad * 8);

  const u16* kbase = qkv + (size_t)(b * 1024) * 2304 + 768 + h * 64;
  const u16* vbase = vT + (size_t)(bh * 64) * 1024;
  u16* Pw = Ps[w];

  f32x4 accO[4];
  float l_loc = 0.f;
#pragma unroll
  for (int dj = 0; dj < 4; dj++) accO[dj] = (f32x4){0.f, 0.f, 0.f, 0.f};

  auto stage = [&](int buf, int kb) {
#pragma unroll
    for (int pass = 0; pass < 2; pass++) {
      int u = pass * 256 + t;                  // 16B unit, 0..511
      int ks = u >> 8, row = (u >> 2) & 63, c4 = u & 3;
      int cs = c4 ^ ((row >> 1) & 3);          // pre-swizzled source column
      g2l16(kbase + (size_t)(kb + row) * 2304 + ks * 32 + cs * 8, Ks[buf] + (size_t)u * 8);
      g2l16(vbase + (size_t)row * 1024 + kb + ks * 32 + cs * 8, Vs[buf] + (size_t)u * 8);
    }
  };

  stage(0, 0);
  __syncthreads();
  int cur = 0;
  for (int kb = 0; kb < 1024; kb += 64) {
    if (kb + 64 < 1024) stage(cur ^ 1, kb + 64);   // prefetch next tile

    f32x4 s[4];
#pragma unroll
    for (int nj = 0; nj < 4; nj++) s[nj] = (f32x4){0.f, 0.f, 0.f, 0.f};
#pragma unroll
    for (int ks = 0; ks < 2; ks++)
#pragma unroll
      for (int nj = 0; nj < 4; nj++) {
        short8 ak = *(const short8*)(Ks[cur] + ks * 2048 + (nj * 16 + lr) * 32 + (quad ^ swz) * 8);
        s[nj] = __builtin_amdgcn_mfma_f32_16x16x32_bf16(ak, aq[ks], s[nj], 0, 0, 0);
      }

    {
      const int rowoff = lr * 72;
#pragma unroll
      for (int nj = 0; nj < 4; nj++) {
        s16x4 pk;
#pragma unroll
        for (int r = 0; r < 4; r++) {
          float p = exp2f(s[nj][r] * 0.18033688011112042f);
          l_loc += p;
          pk[r] = (short)f2bf(p);
        }
        *(s16x4*)(Pw + rowoff + nj * 16 + quad * 4) = pk;
      }
    }

#pragma unroll
    for (int ks = 0; ks < 2; ks++) {
      short8 bp = *(const short8*)(Pw + lr * 72 + ks * 32 + quad * 8);
#pragma unroll
      for (int dj = 0; dj < 4; dj++) {
        short8 av = *(const short8*)(Vs[cur] + ks * 2048 + (dj * 16 + lr) * 32 + (quad ^ swz) * 8);
        accO[dj] = __builtin_amdgcn_mfma_f32_16x16x32_bf16(av, bp, accO[dj], 0, 0, 0);
      }
    }
    __syncthreads();
    cur ^= 1;
  }

  l_loc += __shfl_xor(l_loc, 16);
  l_loc += __shfl_xor(l_loc, 32);
  {
    float inv = 1.0f / l_loc;
    size_t grow = (size_t)(b * 1024 + qb + lr);
#pragma unroll
    for (int dj = 0; dj < 4; dj++) {
      s16x4 ov;
#pragma unroll
      for (int r = 0; r < 4; r++) ov[r] = (short)f2bf(accO[dj][r] * inv);
      *(s16x4*)(o + grow * 768 + h * 64 + dj * 16 + quad * 4) = ov;
    }
  }
}

// ---------------- driver ----------------
extern "C" void kernel_launch(void* const* d_in, const int* in_sizes, int n_in,
                              void* d_out, int out_size, void* d_ws, size_t ws_size,
                              hipStream_t stream) {
  (void)in_sizes; (void)n_in; (void)out_size; (void)ws_size;
  const float* c_f    = (const float*)d_in[0];
  const float* conv_w = (const float*)d_in[1];
  const float* conv_b = (const float*)d_in[2];
  const float* ln1_w  = (const float*)d_in[3];
  const float* ln1_b  = (const float*)d_in[4];
  const float* qkv_w  = (const float*)d_in[5];
  const float* out_w  = (const float*)d_in[6];
  const float* out_b  = (const float*)d_in[7];
  const float* ln2_w  = (const float*)d_in[8];
  const float* ln2_b  = (const float*)d_in[9];
  const float* m1w    = (const float*)d_in[10];
  const float* m1b    = (const float*)d_in[11];
  const float* m2w    = (const float*)d_in[12];
  const float* m2b    = (const float*)d_in[13];
  float* out = (float*)d_out;

  // Memory layout (total 88,997,888 B — proven to fit; all sizes 256-aligned):
  //   x | y | qkvb | ob | hb | aconv | convw | wqkv | wout | wm1 | pos | wm2
  // pos (3.15M) is placed between wm1 and wm2: it is dead after the conv
  // epilogue, making aconv..wm1+pos a contiguous >=12.58M dead region during
  // the mlp2->redln window.
  //
  // mlp2 split-K=4 partials (12.58M each), live mlp2(l) -> redln-ln1(l+1):
  //   pm0 = qkvb[0..12.58M)          (qkvb dead after attn)
  //   pm1 = qkvb[12.58M..) + ob      (ob dead after out-proj)
  //   pm2 = d_out                    (scratch until final out_tr)
  //   pm3 = aconv..wm1 + 0.65M of pos (weights dead; redln(l+1) runs BEFORE
  //         wconv(l+1) so partial reads precede weight rewrites)
  // out-proj split-K=2 partials, live out-proj(l) -> redln-ln2(l):
  //   po0 = qkvb[0..12.58M)          (NOT ob -- ob is out-proj's A operand)
  //   po1 = d_out
  const size_t PSZ = 4096ull * 768 * 4;                 // 12,582,912

  char* p = (char*)d_ws;
  auto alloc = [&](size_t bytes) { char* q = p; p += (bytes + 255) & ~(size_t)255; return q; };
  float* x    = (float*)alloc(4096ull * 768 * 4);
  u16* y      = (u16*)alloc(4096ull * 768 * 2);
  u16* qkvb   = (u16*)alloc(4096ull * 2304 * 2);
  u16* ob     = (u16*)alloc(4096ull * 768 * 2);
  u16* hb     = (u16*)alloc(4096ull * 3072 * 2);
  u16* aconv  = (u16*)alloc(4096ull * 256 * 2);
  u16* convw  = (u16*)alloc(768ull * 256 * 2);
  u16* wqkv   = (u16*)alloc(2304ull * 768 * 2);
  u16* wout   = (u16*)alloc(768ull * 768 * 2);
  u16* wm1    = (u16*)alloc(3072ull * 768 * 2);
  float* pos  = (float*)alloc(1024ull * 768 * 4);       // dead after conv epilogue
  u16* wm2    = (u16*)alloc(768ull * 3072 * 2);
  // vT [48][64][1024] bf16 (6.3 MB) aliases hb (25 MB): hb dead during attn.
  u16* vT = hb;

  P4 pm{};   // mlp2 partials (split-K=4)
  pm.p[0] = (float*)qkvb;
  pm.p[1] = (float*)((char*)qkvb + PSZ);
  pm.p[2] = (float*)out;
  pm.p[3] = (float*)aconv;     // aconv..wm1 (11.93M) + head of pos (0.65M)
  P4 po{};   // out-proj partials (split-K=2)
  po.p[0] = (float*)qkvb;
  po.p[1] = (float*)out;
  P4 none{};

  pos_kernel<<<1024, 256, 0, stream>>>(pos);
  convw_kernel<<<768, 256, 0, stream>>>(conv_w, convw);
  cf_tr_kernel<<<dim3(32, 8, 4), 256, 0, stream>>>(c_f, aconv);
  gemm_bt<EPI_BIAS_POS><<<dim3(6, 32), 256, 0, stream>>>(aconv, convw, conv_b, pos, x, 4096, 768, 256, none);

  for (int lyr = 0; lyr < 8; lyr++) {
    // redln FIRST (reads mlp2 partials incl. the weight region), THEN wconv
    if (lyr == 0) {
      ln_kernel<<<4096, 256, 0, stream>>>(x, ln1_w, ln1_b, y);
    } else {
      redln_kernel<4, true><<<4096, 256, 0, stream>>>(pm, x, m2b + (lyr - 1) * 768,
                                                      ln1_w + lyr * 768, ln1_b + lyr * 768, x, y);
    }
    wconv_kernel<<<6912, 256, 0, stream>>>(qkv_w, out_w, m1w, m2w, wqkv, wout, wm1, wm2, lyr);
    gemm_bt<EPI_BF16><<<dim3(18, 32), 256, 0, stream>>>(y, wqkv, nullptr, nullptr, qkvb, 4096, 2304, 768, none);
    vtr_kernel<<<dim3(16, 48), 256, 0, stream>>>(qkvb, vT);
    attn_kernel<<<dim3(16, 48), 256, 0, stream>>>(qkvb, vT, ob);
    // out-proj: split-K=2 into fp32 partials; combined+LN2 by redln below
    gemm_bt<EPI_PART><<<dim3(6, 32, 2), 256, 0, stream>>>(ob, wout, nullptr, nullptr, nullptr, 4096, 768, 768, po);
    redln_kernel<2, true><<<4096, 256, 0, stream>>>(po, x, out_b + lyr * 768,
                                                    ln2_w + lyr * 768, ln2_b + lyr * 768, x, y);
    gemm_bt<EPI_BIAS_GELU><<<dim3(24, 32), 256, 0, stream>>>(y, wm1, m1b + lyr * 3072, nullptr, hb, 4096, 3072, 768, none);
    // mlp2: split-K=4 into fp32 partials (768 blocks -> 3 blocks/CU)
    gemm_bt<EPI_PART><<<dim3(6, 32, 4), 256, 0, stream>>>(hb, wm2, nullptr, nullptr, nullptr, 4096, 768, 3072, pm);
  }
  // final combine (no LN needed; consumer is the output transpose)
  redln_kernel<4, false><<<4096, 256, 0, stream>>>(pm, x, m2b + 7 * 768, nullptr, nullptr, x, nullptr);
  out_tr_kernel<<<dim3(24, 32, 4), 256, 0, stream>>>(x, out);
}

// Round 7
// 1678.038 us; speedup vs baseline: 1.0193x; 1.0062x over previous
//
#include <hip/hip_runtime.h>
#include <stdint.h>

typedef unsigned short u16;
typedef __attribute__((ext_vector_type(8))) short short8;
typedef __attribute__((ext_vector_type(4))) short s16x4;
typedef __attribute__((ext_vector_type(4))) float f32x4;

struct P4 { float* p[4]; };

#define DEV __device__ __forceinline__

DEV u16 f2bf(float f) {
  union { float f; uint32_t u; } c; c.f = f;
  uint32_t u = c.u;
  uint32_t r = u + 0x7fffu + ((u >> 16) & 1u);  // RNE
  return (u16)(r >> 16);
}

DEV void g2l16(const void* g, void* l) {
  __builtin_amdgcn_global_load_lds((__attribute__((address_space(1))) void*)(g),
                                   (__attribute__((address_space(3))) void*)(l),
                                   16, 0, 0);
}

// ---------------- positional embedding (PositionEmbeddingSine) ----------------
__global__ void pos_kernel(float* __restrict__ pos) {
  int n = blockIdx.x;
  float yv = (float)((n >> 5) + 1) / (32.0f + 1e-6f) * 6.283185307179586f;
  float xv = (float)((n & 31) + 1) / (32.0f + 1e-6f) * 6.283185307179586f;
#pragma unroll
  for (int i = 0; i < 3; i++) {
    int d = threadIdx.x + i * 256;
    int dd = (d < 384) ? d : d - 384;
    float base = (d < 384) ? yv : xv;
    float ex = (float)(dd & ~1) / 384.0f;     // 2*floor(dd/2)/384
    float arg = base / powf(10000.0f, ex);
    pos[(size_t)n * 768 + d] = (dd & 1) ? cosf(arg) : sinf(arg);
  }
}

// ---------------- conv_w fp32 [768][256] -> bf16 (already N x K) ----------------
__global__ void convw_kernel(const float* __restrict__ src, u16* __restrict__ dst) {
  int i = blockIdx.x * 256 + threadIdx.x;
  dst[i] = f2bf(src[i]);
}

// ---------------- 32x32 tile transpose fp32 -> bf16 ----------------
DEV void tile_tr32(const float* __restrict__ src, u16* __restrict__ dst,
                   int R, int C, int tr, int tc, float (*tile)[33]) {
  int tx = threadIdx.x & 31, ty = threadIdx.x >> 5;  // 32 x 8
#pragma unroll
  for (int i = 0; i < 32; i += 8)
    tile[ty + i][tx] = src[(size_t)(tr * 32 + ty + i) * C + tc * 32 + tx];
  __syncthreads();
#pragma unroll
  for (int i = 0; i < 32; i += 8)
    dst[(size_t)(tc * 32 + ty + i) * R + tr * 32 + tx] = f2bf(tile[tx][ty + i]);
}

// all four weights of one layer, transposed to [N][K] bf16, one launch
__global__ void wconv_kernel(const float* __restrict__ qkv_w, const float* __restrict__ out_w,
                             const float* __restrict__ m1w, const float* __restrict__ m2w,
                             u16* __restrict__ wqkv, u16* __restrict__ wout,
                             u16* __restrict__ wm1, u16* __restrict__ wm2, int layer) {
  __shared__ float tile[32][33];
  int tid = blockIdx.x;
  if (tid < 1728) {                                   // qkv_w: [768][2304] -> [2304][768]
    tile_tr32(qkv_w + (size_t)layer * 768 * 2304, wqkv, 768, 2304, tid / 72, tid % 72, tile);
  } else if (tid < 2304) {                            // out_w: [768][768]
    int t2 = tid - 1728;
    tile_tr32(out_w + (size_t)layer * 768 * 768, wout, 768, 768, t2 / 24, t2 % 24, tile);
  } else if (tid < 4608) {                            // mlp_w1: [768][3072] -> [3072][768]
    int t3 = tid - 2304;
    tile_tr32(m1w + (size_t)layer * 768 * 3072, wm1, 768, 3072, t3 / 96, t3 % 96, tile);
  } else {                                            // mlp_w2: [3072][768] -> [768][3072]
    int t4 = tid - 4608;
    tile_tr32(m2w + (size_t)layer * 3072 * 768, wm2, 3072, 768, t4 / 24, t4 % 24, tile);
  }
}

// c_f [B][256][1024] fp32 -> aconv [B][1024][256] bf16
__global__ void cf_tr_kernel(const float* __restrict__ c_f, u16* __restrict__ aconv) {
  __shared__ float tile[32][33];
  int b = blockIdx.z;
  tile_tr32(c_f + (size_t)b * 256 * 1024, aconv + (size_t)b * 1024 * 256,
            256, 1024, blockIdx.y, blockIdx.x, tile);
}

// x [B][1024][768] fp32 -> out [B][768][1024] fp32
__global__ void out_tr_kernel(const float* __restrict__ x, float* __restrict__ out) {
  __shared__ float tile[32][33];
  int b = blockIdx.z;
  const float* src = x + (size_t)b * 1024 * 768;
  float* dst = out + (size_t)b * 768 * 1024;
  int tr = blockIdx.y, tc = blockIdx.x;  // tr over n (32 tiles), tc over d (24 tiles)
  int tx = threadIdx.x & 31, ty = threadIdx.x >> 5;
#pragma unroll
  for (int i = 0; i < 32; i += 8)
    tile[ty + i][tx] = src[(size_t)(tr * 32 + ty + i) * 768 + tc * 32 + tx];
  __syncthreads();
#pragma unroll
  for (int i = 0; i < 32; i += 8)
    dst[(size_t)(tc * 32 + ty + i) * 1024 + tr * 32 + tx] = tile[tx][ty + i];
}

// ---------------- LayerNorm: fp32 in -> bf16 out ----------------
__global__ __launch_bounds__(256) void ln_kernel(const float* __restrict__ x,
                                                 const float* __restrict__ w,
                                                 const float* __restrict__ bsh,
                                                 u16* __restrict__ y) {
  int row = blockIdx.x, t = threadIdx.x;
  const float* xr = x + (size_t)row * 768;
  float v[3], s = 0.f, sq = 0.f;
#pragma unroll
  for (int i = 0; i < 3; i++) { v[i] = xr[t + i * 256]; s += v[i]; sq += v[i] * v[i]; }
#pragma unroll
  for (int off = 32; off; off >>= 1) { s += __shfl_xor(s, off); sq += __shfl_xor(sq, off); }
  __shared__ float ss[4], ssq[4];
  if ((t & 63) == 0) { ss[t >> 6] = s; ssq[t >> 6] = sq; }
  __syncthreads();
  s = ss[0] + ss[1] + ss[2] + ss[3];
  sq = ssq[0] + ssq[1] + ssq[2] + ssq[3];
  float mean = s * (1.0f / 768.0f);
  float var = sq * (1.0f / 768.0f) - mean * mean;
  float rs = rsqrtf(var + 1e-5f);
#pragma unroll
  for (int i = 0; i < 3; i++) {
    int c = t + i * 256;
    y[(size_t)row * 768 + c] = f2bf((v[i] - mean) * rs * w[c] + bsh[c]);
  }
}

// ---------------- fused split-K reduce (+ bias + residual) and LayerNorm ----------------
template <int S, bool DO_LN>
__global__ __launch_bounds__(256) void redln_kernel(P4 parts, const float* __restrict__ xin,
                                                    const float* __restrict__ bias,
                                                    const float* __restrict__ w,
                                                    const float* __restrict__ bsh,
                                                    float* __restrict__ xout,
                                                    u16* __restrict__ y) {
  int row = blockIdx.x, t = threadIdx.x;
  size_t base = (size_t)row * 768;
  float v[3], s = 0.f, sq = 0.f;
#pragma unroll
  for (int i = 0; i < 3; i++) {
    int c = t + i * 256;
    float acc = xin[base + c] + bias[c];
#pragma unroll
    for (int j = 0; j < S; j++) acc += parts.p[j][base + c];
    v[i] = acc;
    xout[base + c] = acc;
    s += acc; sq += acc * acc;
  }
  if constexpr (DO_LN) {
#pragma unroll
    for (int off = 32; off; off >>= 1) { s += __shfl_xor(s, off); sq += __shfl_xor(sq, off); }
    __shared__ float ss[4], ssq[4];
    if ((t & 63) == 0) { ss[t >> 6] = s; ssq[t >> 6] = sq; }
    __syncthreads();
    s = ss[0] + ss[1] + ss[2] + ss[3];
    sq = ssq[0] + ssq[1] + ssq[2] + ssq[3];
    float mean = s * (1.0f / 768.0f);
    float var = sq * (1.0f / 768.0f) - mean * mean;
    float rs = rsqrtf(var + 1e-5f);
#pragma unroll
    for (int i = 0; i < 3; i++) {
      int c = t + i * 256;
      y[base + c] = f2bf((v[i] - mean) * rs * w[c] + bsh[c]);
    }
  }
}

// ---------------- GEMM: C[M,N] = A[M,K](bf16) @ BT[N,K](bf16)^T ----------------
// BN template param: 128 (waves 2x2, 64x64 each) or 64 (waves 2x2, 64x32 each).
// BN=64 doubles the grid for N=768 shapes (12x32=384 blocks) with a fused
// epilogue — occupancy from tile shape instead of split-K (K too short there).
constexpr int EPI_BF16 = 0, EPI_BIAS_RES = 1, EPI_BIAS_GELU = 2, EPI_BIAS_POS = 3, EPI_PART = 4;

template <int EPI, int BN = 128>
__global__ __launch_bounds__(256, 2) void gemm_bt(
    const u16* __restrict__ A, const u16* __restrict__ BT,
    const float* __restrict__ bias, const float* __restrict__ res,
    void* __restrict__ Cout, int M, int N, int K, P4 parts) {
  constexpr int NF = BN / 32;                       // N fragments per wave (4 or 2)
  __shared__ __align__(16) u16 As[128 * 32];
  __shared__ __align__(16) u16 Bs[BN * 32];
  const int t = threadIdx.x;
  const int w = t >> 6, l = t & 63, lr = l & 15, quad = l >> 4;
  const int bm = blockIdx.y * 128, bn = blockIdx.x * BN;
  const int wm = (w & 1) * 64, wn = (w >> 1) * (BN / 2);
  f32x4 acc[4][NF];
#pragma unroll
  for (int i = 0; i < 4; i++)
#pragma unroll
    for (int j = 0; j < NF; j++) acc[i][j] = (f32x4){0.f, 0.f, 0.f, 0.f};
  const int c0 = t, c1 = 256 + t;
  const size_t a0 = (size_t)(bm + (c0 >> 2)) * K + (c0 & 3) * 8;
  const size_t a1 = (size_t)(bm + (c1 >> 2)) * K + (c1 & 3) * 8;
  const size_t b0 = (size_t)(bn + (c0 >> 2)) * K + (c0 & 3) * 8;
  const size_t b1 = (BN == 128) ? (size_t)(bn + (c1 >> 2)) * K + (c1 & 3) * 8 : 0;
  const int kc = K / (int)gridDim.z;                // K-chunk for split-K (kc==K if z==1)
  const int kBeg = (int)blockIdx.z * kc;
  for (int k0 = kBeg; k0 < kBeg + kc; k0 += 32) {
    g2l16(A + a0 + k0, As + c0 * 8);
    g2l16(A + a1 + k0, As + c1 * 8);
    g2l16(BT + b0 + k0, Bs + c0 * 8);
    if constexpr (BN == 128) g2l16(BT + b1 + k0, Bs + c1 * 8);
    __syncthreads();
    short8 af[4], bf[NF];
#pragma unroll
    for (int mi = 0; mi < 4; mi++) af[mi] = *(const short8*)(As + (wm + mi * 16 + lr) * 32 + quad * 8);
#pragma unroll
    for (int nj = 0; nj < NF; nj++) bf[nj] = *(const short8*)(Bs + (wn + nj * 16 + lr) * 32 + quad * 8);
#pragma unroll
    for (int mi = 0; mi < 4; mi++)
#pragma unroll
      for (int nj = 0; nj < NF; nj++)
        acc[mi][nj] = __builtin_amdgcn_mfma_f32_16x16x32_bf16(af[mi], bf[nj], acc[mi][nj], 0, 0, 0);
    __syncthreads();
  }
  float* Pc = (EPI == EPI_PART) ? parts.p[blockIdx.z] : nullptr;
#pragma unroll
  for (int mi = 0; mi < 4; mi++) {
    const int rowb = bm + wm + mi * 16 + quad * 4;
#pragma unroll
    for (int nj = 0; nj < NF; nj++) {
      const int gn = bn + wn + nj * 16 + lr;
#pragma unroll
      for (int r = 0; r < 4; r++) {
        const size_t idx = (size_t)(rowb + r) * N + gn;
        float v = acc[mi][nj][r];
        if constexpr (EPI == EPI_BF16) {
          ((u16*)Cout)[idx] = f2bf(v);
        } else if constexpr (EPI == EPI_BIAS_RES) {
          ((float*)Cout)[idx] = v + bias[gn] + res[idx];
        } else if constexpr (EPI == EPI_BIAS_GELU) {
          float xg = v + bias[gn];
          ((u16*)Cout)[idx] = f2bf(0.5f * xg * (1.0f + erff(xg * 0.70710678118f)));
        } else if constexpr (EPI == EPI_BIAS_POS) {  // conv epilogue, N==768
          ((float*)Cout)[idx] = v + bias[gn] + res[(size_t)((rowb + r) & 1023) * N + gn];
        } else {  // EPI_PART: fp32 partial, combined later by redln_kernel
          Pc[idx] = v;
        }
      }
    }
  }
}

// ---------------- V transpose: qkvb v-cols [4096][2304] -> vT [48][64][1024] ----------------
__global__ __launch_bounds__(256) void vtr_kernel(const u16* __restrict__ qkvb,
                                                  u16* __restrict__ vT) {
  __shared__ uint32_t tile[64][65];
  const int t = threadIdx.x;
  const int bh = blockIdx.y, b = bh / 12, h = bh % 12;
  const int tok0 = blockIdx.x * 64;
  {
    int trow = t >> 2, dc = (t & 3) * 16;
    const u16* src = qkvb + (size_t)(b * 1024 + tok0 + trow) * 2304 + 1536 + h * 64 + dc;
    short8 v0 = *(const short8*)src;
    short8 v1 = *(const short8*)(src + 8);
#pragma unroll
    for (int j = 0; j < 8; j++) {
      tile[trow][dc + j] = (uint32_t)(u16)v0[j];
      tile[trow][dc + 8 + j] = (uint32_t)(u16)v1[j];
    }
  }
  __syncthreads();
  {
    int d = t >> 2, tc = (t & 3) * 16;
    short8 o0, o1;
#pragma unroll
    for (int j = 0; j < 8; j++) {
      o0[j] = (short)(u16)tile[tc + j][d];
      o1[j] = (short)(u16)tile[tc + 8 + j][d];
    }
    u16* dst = vT + (size_t)(bh * 64 + d) * 1024 + tok0 + tc;
    *(short8*)dst = o0;
    *(short8*)(dst + 8) = o1;
  }
}

// ---------------- flash attention, S^T formulation, v2 ----------------
// (unchanged — verified: 4 waves, double-buffer, swizzled K/V)
__global__ __launch_bounds__(256, 3) void attn_kernel(const u16* __restrict__ qkv,
                                                      const u16* __restrict__ vT,
                                                      u16* __restrict__ o) {
  __shared__ __align__(16) u16 Ks[2][2 * 64 * 32];   // [buf][ks][key][32]
  __shared__ __align__(16) u16 Vs[2][2 * 64 * 32];   // [buf][ks][d][32]
  __shared__ __align__(16) u16 Ps[4][16 * 72];       // per-wave P [qlocal][key], pad 72
  const int t = threadIdx.x;
  const int w = t >> 6, l = t & 63, lr = l & 15, quad = l >> 4;
  const int bh = blockIdx.y, b = bh / 12, h = bh % 12;
  const int qb = blockIdx.x * 64 + w * 16;           // 16 q-rows per wave
  const int swz = (lr >> 1) & 3;                     // read-side column xor

  short8 aq[2];
#pragma unroll
  for (int ks = 0; ks < 2; ks++)
    aq[ks] = *(const short8*)(qkv + (size_t)(b * 1024 + qb + lr) * 2304 +
                              h * 64 + ks * 32 + quad * 8);

  const u16* kbase = qkv + (size_t)(b * 1024) * 2304 + 768 + h * 64;
  const u16* vbase = vT + (size_t)(bh * 64) * 1024;
  u16* Pw = Ps[w];

  f32x4 accO[4];
  float l_loc = 0.f;
#pragma unroll
  for (int dj = 0; dj < 4; dj++) accO[dj] = (f32x4){0.f, 0.f, 0.f, 0.f};

  auto stage = [&](int buf, int kb) {
#pragma unroll
    for (int pass = 0; pass < 2; pass++) {
      int u = pass * 256 + t;                  // 16B unit, 0..511
      int ks = u >> 8, row = (u >> 2) & 63, c4 = u & 3;
      int cs = c4 ^ ((row >> 1) & 3);          // pre-swizzled source column
      g2l16(kbase + (size_t)(kb + row) * 2304 + ks * 32 + cs * 8, Ks[buf] + (size_t)u * 8);
      g2l16(vbase + (size_t)row * 1024 + kb + ks * 32 + cs * 8, Vs[buf] + (size_t)u * 8);
    }
  };

  stage(0, 0);
  __syncthreads();
  int cur = 0;
  for (int kb = 0; kb < 1024; kb += 64) {
    if (kb + 64 < 1024) stage(cur ^ 1, kb + 64);   // prefetch next tile

    f32x4 s[4];
#pragma unroll
    for (int nj = 0; nj < 4; nj++) s[nj] = (f32x4){0.f, 0.f, 0.f, 0.f};
#pragma unroll
    for (int ks = 0; ks < 2; ks++)
#pragma unroll
      for (int nj = 0; nj < 4; nj++) {
        short8 ak = *(const short8*)(Ks[cur] + ks * 2048 + (nj * 16 + lr) * 32 + (quad ^ swz) * 8);
        s[nj] = __builtin_amdgcn_mfma_f32_16x16x32_bf16(ak, aq[ks], s[nj], 0, 0, 0);
      }

    {
      const int rowoff = lr * 72;
#pragma unroll
      for (int nj = 0; nj < 4; nj++) {
        s16x4 pk;
#pragma unroll
        for (int r = 0; r < 4; r++) {
          float p = exp2f(s[nj][r] * 0.18033688011112042f);
          l_loc += p;
          pk[r] = (short)f2bf(p);
        }
        *(s16x4*)(Pw + rowoff + nj * 16 + quad * 4) = pk;
      }
    }

#pragma unroll
    for (int ks = 0; ks < 2; ks++) {
      short8 bp = *(const short8*)(Pw + lr * 72 + ks * 32 + quad * 8);
#pragma unroll
      for (int dj = 0; dj < 4; dj++) {
        short8 av = *(const short8*)(Vs[cur] + ks * 2048 + (dj * 16 + lr) * 32 + (quad ^ swz) * 8);
        accO[dj] = __builtin_amdgcn_mfma_f32_16x16x32_bf16(av, bp, accO[dj], 0, 0, 0);
      }
    }
    __syncthreads();
    cur ^= 1;
  }

  l_loc += __shfl_xor(l_loc, 16);
  l_loc += __shfl_xor(l_loc, 32);
  {
    float inv = 1.0f / l_loc;
    size_t grow = (size_t)(b * 1024 + qb + lr);
#pragma unroll
    for (int dj = 0; dj < 4; dj++) {
      s16x4 ov;
#pragma unroll
      for (int r = 0; r < 4; r++) ov[r] = (short)f2bf(accO[dj][r] * inv);
      *(s16x4*)(o + grow * 768 + h * 64 + dj * 16 + quad * 4) = ov;
    }
  }
}

// ---------------- driver ----------------
extern "C" void kernel_launch(void* const* d_in, const int* in_sizes, int n_in,
                              void* d_out, int out_size, void* d_ws, size_t ws_size,
                              hipStream_t stream) {
  (void)in_sizes; (void)n_in; (void)out_size; (void)ws_size;
  const float* c_f    = (const float*)d_in[0];
  const float* conv_w = (const float*)d_in[1];
  const float* conv_b = (const float*)d_in[2];
  const float* ln1_w  = (const float*)d_in[3];
  const float* ln1_b  = (const float*)d_in[4];
  const float* qkv_w  = (const float*)d_in[5];
  const float* out_w  = (const float*)d_in[6];
  const float* out_b  = (const float*)d_in[7];
  const float* ln2_w  = (const float*)d_in[8];
  const float* ln2_b  = (const float*)d_in[9];
  const float* m1w    = (const float*)d_in[10];
  const float* m1b    = (const float*)d_in[11];
  const float* m2w    = (const float*)d_in[12];
  const float* m2b    = (const float*)d_in[13];
  float* out = (float*)d_out;

  // Memory layout (R6-verified):
  //   x | y | qkvb | ob | hb | aconv | convw | wqkv | wout | wm1 | pos | wm2
  // mlp2 split-K=4 partials (12.58M each), live mlp2(l) -> redln-ln1(l+1):
  //   pm0 = qkvb[0..12.58M), pm1 = qkvb[12.58M..)+ob, pm2 = d_out,
  //   pm3 = aconv..wm1 + head of pos (redln runs BEFORE wconv of next layer)
  const size_t PSZ = 4096ull * 768 * 4;                 // 12,582,912

  char* p = (char*)d_ws;
  auto alloc = [&](size_t bytes) { char* q = p; p += (bytes + 255) & ~(size_t)255; return q; };
  float* x    = (float*)alloc(4096ull * 768 * 4);
  u16* y      = (u16*)alloc(4096ull * 768 * 2);
  u16* qkvb   = (u16*)alloc(4096ull * 2304 * 2);
  u16* ob     = (u16*)alloc(4096ull * 768 * 2);
  u16* hb     = (u16*)alloc(4096ull * 3072 * 2);
  u16* aconv  = (u16*)alloc(4096ull * 256 * 2);
  u16* convw  = (u16*)alloc(768ull * 256 * 2);
  u16* wqkv   = (u16*)alloc(2304ull * 768 * 2);
  u16* wout   = (u16*)alloc(768ull * 768 * 2);
  u16* wm1    = (u16*)alloc(3072ull * 768 * 2);
  float* pos  = (float*)alloc(1024ull * 768 * 4);       // dead after conv epilogue
  u16* wm2    = (u16*)alloc(768ull * 3072 * 2);
  // vT [48][64][1024] bf16 (6.3 MB) aliases hb (25 MB): hb dead during attn.
  u16* vT = hb;

  P4 pm{};   // mlp2 partials (split-K=4)
  pm.p[0] = (float*)qkvb;
  pm.p[1] = (float*)((char*)qkvb + PSZ);
  pm.p[2] = (float*)out;
  pm.p[3] = (float*)aconv;     // aconv..wm1 (11.93M) + head of pos (0.65M)
  P4 none{};

  pos_kernel<<<1024, 256, 0, stream>>>(pos);
  convw_kernel<<<768, 256, 0, stream>>>(conv_w, convw);
  cf_tr_kernel<<<dim3(32, 8, 4), 256, 0, stream>>>(c_f, aconv);
  gemm_bt<EPI_BIAS_POS, 64><<<dim3(12, 32), 256, 0, stream>>>(aconv, convw, conv_b, pos, x, 4096, 768, 256, none);

  for (int lyr = 0; lyr < 8; lyr++) {
    // redln FIRST (reads mlp2 partials incl. the weight region), THEN wconv
    if (lyr == 0) {
      ln_kernel<<<4096, 256, 0, stream>>>(x, ln1_w, ln1_b, y);
    } else {
      redln_kernel<4, true><<<4096, 256, 0, stream>>>(pm, x, m2b + (lyr - 1) * 768,
                                                      ln1_w + lyr * 768, ln1_b + lyr * 768, x, y);
    }
    wconv_kernel<<<6912, 256, 0, stream>>>(qkv_w, out_w, m1w, m2w, wqkv, wout, wm1, wm2, lyr);
    gemm_bt<EPI_BF16><<<dim3(18, 32), 256, 0, stream>>>(y, wqkv, nullptr, nullptr, qkvb, 4096, 2304, 768, none);
    vtr_kernel<<<dim3(16, 48), 256, 0, stream>>>(qkvb, vT);
    attn_kernel<<<dim3(16, 48), 256, 0, stream>>>(qkvb, vT, ob);
    // out-proj: BN=64 tile -> 384 blocks, fused bias+residual epilogue
    gemm_bt<EPI_BIAS_RES, 64><<<dim3(12, 32), 256, 0, stream>>>(ob, wout, out_b + lyr * 768, x, x, 4096, 768, 768, none);
    ln_kernel<<<4096, 256, 0, stream>>>(x, ln2_w + lyr * 768, ln2_b + lyr * 768, y);
    gemm_bt<EPI_BIAS_GELU><<<dim3(24, 32), 256, 0, stream>>>(y, wm1, m1b + lyr * 3072, nullptr, hb, 4096, 3072, 768, none);
    // mlp2: split-K=4 into fp32 partials (768 blocks -> 3 blocks/CU)
    gemm_bt<EPI_PART><<<dim3(6, 32, 4), 256, 0, stream>>>(hb, wm2, nullptr, nullptr, nullptr, 4096, 768, 3072, pm);
  }
  // final combine (no LN needed; consumer is the output transpose)
  redln_kernel<4, false><<<4096, 256, 0, stream>>>(pm, x, m2b + 7 * 768, nullptr, nullptr, x, nullptr);
  out_tr_kernel<<<dim3(24, 32, 4), 256, 0, stream>>>(x, out);
}

// Round 8
// 1670.214 us; speedup vs baseline: 1.0241x; 1.0047x over previous
//
#include <hip/hip_runtime.h>
#include <stdint.h>

typedef unsigned short u16;
typedef __attribute__((ext_vector_type(8))) short short8;
typedef __attribute__((ext_vector_type(4))) short s16x4;
typedef __attribute__((ext_vector_type(4))) float f32x4;

struct P4 { float* p[4]; };

#define DEV __device__ __forceinline__

DEV u16 f2bf(float f) {
  union { float f; uint32_t u; } c; c.f = f;
  uint32_t u = c.u;
  uint32_t r = u + 0x7fffu + ((u >> 16) & 1u);  // RNE
  return (u16)(r >> 16);
}

DEV void g2l16(const void* g, void* l) {
  __builtin_amdgcn_global_load_lds((__attribute__((address_space(1))) void*)(g),
                                   (__attribute__((address_space(3))) void*)(l),
                                   16, 0, 0);
}

// ---------------- positional embedding (PositionEmbeddingSine) ----------------
__global__ void pos_kernel(float* __restrict__ pos) {
  int n = blockIdx.x;
  float yv = (float)((n >> 5) + 1) / (32.0f + 1e-6f) * 6.283185307179586f;
  float xv = (float)((n & 31) + 1) / (32.0f + 1e-6f) * 6.283185307179586f;
#pragma unroll
  for (int i = 0; i < 3; i++) {
    int d = threadIdx.x + i * 256;
    int dd = (d < 384) ? d : d - 384;
    float base = (d < 384) ? yv : xv;
    float ex = (float)(dd & ~1) / 384.0f;     // 2*floor(dd/2)/384
    float arg = base / powf(10000.0f, ex);
    pos[(size_t)n * 768 + d] = (dd & 1) ? cosf(arg) : sinf(arg);
  }
}

// ---------------- conv_w fp32 [768][256] -> bf16 (already N x K) ----------------
__global__ void convw_kernel(const float* __restrict__ src, u16* __restrict__ dst) {
  int i = blockIdx.x * 256 + threadIdx.x;
  dst[i] = f2bf(src[i]);
}

// ---------------- 32x32 tile transpose fp32 -> bf16 ----------------
DEV void tile_tr32(const float* __restrict__ src, u16* __restrict__ dst,
                   int R, int C, int tr, int tc, float (*tile)[33]) {
  int tx = threadIdx.x & 31, ty = threadIdx.x >> 5;  // 32 x 8
#pragma unroll
  for (int i = 0; i < 32; i += 8)
    tile[ty + i][tx] = src[(size_t)(tr * 32 + ty + i) * C + tc * 32 + tx];
  __syncthreads();
#pragma unroll
  for (int i = 0; i < 32; i += 8)
    dst[(size_t)(tc * 32 + ty + i) * R + tr * 32 + tx] = f2bf(tile[tx][ty + i]);
}

// all four weights of one layer, transposed to [N][K] bf16, one launch
__global__ void wconv_kernel(const float* __restrict__ qkv_w, const float* __restrict__ out_w,
                             const float* __restrict__ m1w, const float* __restrict__ m2w,
                             u16* __restrict__ wqkv, u16* __restrict__ wout,
                             u16* __restrict__ wm1, u16* __restrict__ wm2, int layer) {
  __shared__ float tile[32][33];
  int tid = blockIdx.x;
  if (tid < 1728) {                                   // qkv_w: [768][2304] -> [2304][768]
    tile_tr32(qkv_w + (size_t)layer * 768 * 2304, wqkv, 768, 2304, tid / 72, tid % 72, tile);
  } else if (tid < 2304) {                            // out_w: [768][768]
    int t2 = tid - 1728;
    tile_tr32(out_w + (size_t)layer * 768 * 768, wout, 768, 768, t2 / 24, t2 % 24, tile);
  } else if (tid < 4608) {                            // mlp_w1: [768][3072] -> [3072][768]
    int t3 = tid - 2304;
    tile_tr32(m1w + (size_t)layer * 768 * 3072, wm1, 768, 3072, t3 / 96, t3 % 96, tile);
  } else {                                            // mlp_w2: [3072][768] -> [768][3072]
    int t4 = tid - 4608;
    tile_tr32(m2w + (size_t)layer * 3072 * 768, wm2, 3072, 768, t4 / 24, t4 % 24, tile);
  }
}

// c_f [B][256][1024] fp32 -> aconv [B][1024][256] bf16
__global__ void cf_tr_kernel(const float* __restrict__ c_f, u16* __restrict__ aconv) {
  __shared__ float tile[32][33];
  int b = blockIdx.z;
  tile_tr32(c_f + (size_t)b * 256 * 1024, aconv + (size_t)b * 1024 * 256,
            256, 1024, blockIdx.y, blockIdx.x, tile);
}

// x [B][1024][768] fp32 -> out [B][768][1024] fp32
__global__ void out_tr_kernel(const float* __restrict__ x, float* __restrict__ out) {
  __shared__ float tile[32][33];
  int b = blockIdx.z;
  const float* src = x + (size_t)b * 1024 * 768;
  float* dst = out + (size_t)b * 768 * 1024;
  int tr = blockIdx.y, tc = blockIdx.x;  // tr over n (32 tiles), tc over d (24 tiles)
  int tx = threadIdx.x & 31, ty = threadIdx.x >> 5;
#pragma unroll
  for (int i = 0; i < 32; i += 8)
    tile[ty + i][tx] = src[(size_t)(tr * 32 + ty + i) * 768 + tc * 32 + tx];
  __syncthreads();
#pragma unroll
  for (int i = 0; i < 32; i += 8)
    dst[(size_t)(tc * 32 + ty + i) * 1024 + tr * 32 + tx] = tile[tx][ty + i];
}

// ---------------- LayerNorm: fp32 in -> bf16 out ----------------
__global__ __launch_bounds__(256) void ln_kernel(const float* __restrict__ x,
                                                 const float* __restrict__ w,
                                                 const float* __restrict__ bsh,
                                                 u16* __restrict__ y) {
  int row = blockIdx.x, t = threadIdx.x;
  const float* xr = x + (size_t)row * 768;
  float v[3], s = 0.f, sq = 0.f;
#pragma unroll
  for (int i = 0; i < 3; i++) { v[i] = xr[t + i * 256]; s += v[i]; sq += v[i] * v[i]; }
#pragma unroll
  for (int off = 32; off; off >>= 1) { s += __shfl_xor(s, off); sq += __shfl_xor(sq, off); }
  __shared__ float ss[4], ssq[4];
  if ((t & 63) == 0) { ss[t >> 6] = s; ssq[t >> 6] = sq; }
  __syncthreads();
  s = ss[0] + ss[1] + ss[2] + ss[3];
  sq = ssq[0] + ssq[1] + ssq[2] + ssq[3];
  float mean = s * (1.0f / 768.0f);
  float var = sq * (1.0f / 768.0f) - mean * mean;
  float rs = rsqrtf(var + 1e-5f);
#pragma unroll
  for (int i = 0; i < 3; i++) {
    int c = t + i * 256;
    y[(size_t)row * 768 + c] = f2bf((v[i] - mean) * rs * w[c] + bsh[c]);
  }
}

// ---------------- fused split-K reduce (+ bias + residual) and LayerNorm ----------------
template <int S, bool DO_LN>
__global__ __launch_bounds__(256) void redln_kernel(P4 parts, const float* __restrict__ xin,
                                                    const float* __restrict__ bias,
                                                    const float* __restrict__ w,
                                                    const float* __restrict__ bsh,
                                                    float* __restrict__ xout,
                                                    u16* __restrict__ y) {
  int row = blockIdx.x, t = threadIdx.x;
  size_t base = (size_t)row * 768;
  float v[3], s = 0.f, sq = 0.f;
#pragma unroll
  for (int i = 0; i < 3; i++) {
    int c = t + i * 256;
    float acc = xin[base + c] + bias[c];
#pragma unroll
    for (int j = 0; j < S; j++) acc += parts.p[j][base + c];
    v[i] = acc;
    xout[base + c] = acc;
    s += acc; sq += acc * acc;
  }
  if constexpr (DO_LN) {
#pragma unroll
    for (int off = 32; off; off >>= 1) { s += __shfl_xor(s, off); sq += __shfl_xor(sq, off); }
    __shared__ float ss[4], ssq[4];
    if ((t & 63) == 0) { ss[t >> 6] = s; ssq[t >> 6] = sq; }
    __syncthreads();
    s = ss[0] + ss[1] + ss[2] + ss[3];
    sq = ssq[0] + ssq[1] + ssq[2] + ssq[3];
    float mean = s * (1.0f / 768.0f);
    float var = sq * (1.0f / 768.0f) - mean * mean;
    float rs = rsqrtf(var + 1e-5f);
#pragma unroll
    for (int i = 0; i < 3; i++) {
      int c = t + i * 256;
      y[base + c] = f2bf((v[i] - mean) * rs * w[c] + bsh[c]);
    }
  }
}

// ---------------- GEMM: C[M,N] = A[M,K](bf16) @ BT[N,K](bf16)^T ----------------
// v2: double-buffered LDS with prefetch (one barrier per K-step; the barrier's
// vmcnt drain completes the prefetch) + XOR-swizzled 16B columns
// (stage source col c4 ^ ((row>>1)&3), read col quad ^ ((lr>>1)&3)):
// 8-way bank conflict on ds_read_b128 -> 2-way (free).  Same recipe as the
// R4 attn kernel (verified -35% there).
constexpr int EPI_BF16 = 0, EPI_BIAS_RES = 1, EPI_BIAS_GELU = 2, EPI_BIAS_POS = 3, EPI_PART = 4;

template <int EPI, int BN = 128>
__global__ __launch_bounds__(256, 2) void gemm_bt(
    const u16* __restrict__ A, const u16* __restrict__ BT,
    const float* __restrict__ bias, const float* __restrict__ res,
    void* __restrict__ Cout, int M, int N, int K, P4 parts) {
  constexpr int NF = BN / 32;                       // N fragments per wave (4 or 2)
  __shared__ __align__(16) u16 As[2][128 * 32];
  __shared__ __align__(16) u16 Bs[2][BN * 32];
  const int t = threadIdx.x;
  const int w = t >> 6, l = t & 63, lr = l & 15, quad = l >> 4;
  const int bm = blockIdx.y * 128, bn = blockIdx.x * BN;
  const int wm = (w & 1) * 64, wn = (w >> 1) * (BN / 2);
  const int swz = (lr >> 1) & 3;                    // read-side column xor (lane-const)
  f32x4 acc[4][NF];
#pragma unroll
  for (int i = 0; i < 4; i++)
#pragma unroll
    for (int j = 0; j < NF; j++) acc[i][j] = (f32x4){0.f, 0.f, 0.f, 0.f};
  // staging: unit u -> LDS row u>>2, 16B col u&3; global source col pre-swizzled
  const int c0 = t, c1 = 256 + t;
  const int s0 = (c0 & 3) ^ ((c0 >> 3) & 3);        // swizzled source col of unit c0
  const int s1 = (c1 & 3) ^ ((c1 >> 3) & 3);
  const size_t a0 = (size_t)(bm + (c0 >> 2)) * K + s0 * 8;
  const size_t a1 = (size_t)(bm + (c1 >> 2)) * K + s1 * 8;
  const size_t b0 = (size_t)(bn + (c0 >> 2)) * K + s0 * 8;
  const size_t b1 = (BN == 128) ? (size_t)(bn + (c1 >> 2)) * K + s1 * 8 : 0;
  const int kc = K / (int)gridDim.z;                // K-chunk for split-K (kc==K if z==1)
  const int kBeg = (int)blockIdx.z * kc;

  auto stage = [&](int buf, int k0) {
    g2l16(A + a0 + k0, As[buf] + c0 * 8);
    g2l16(A + a1 + k0, As[buf] + c1 * 8);
    g2l16(BT + b0 + k0, Bs[buf] + c0 * 8);
    if constexpr (BN == 128) g2l16(BT + b1 + k0, Bs[buf] + c1 * 8);
  };

  stage(0, kBeg);
  __syncthreads();
  int cur = 0;
  for (int k0 = kBeg; k0 < kBeg + kc; k0 += 32) {
    if (k0 + 32 < kBeg + kc) stage(cur ^ 1, k0 + 32);   // prefetch next K-tile
    short8 af[4], bf[NF];
#pragma unroll
    for (int mi = 0; mi < 4; mi++)
      af[mi] = *(const short8*)(As[cur] + (wm + mi * 16 + lr) * 32 + (quad ^ swz) * 8);
#pragma unroll
    for (int nj = 0; nj < NF; nj++)
      bf[nj] = *(const short8*)(Bs[cur] + (wn + nj * 16 + lr) * 32 + (quad ^ swz) * 8);
#pragma unroll
    for (int mi = 0; mi < 4; mi++)
#pragma unroll
      for (int nj = 0; nj < NF; nj++)
        acc[mi][nj] = __builtin_amdgcn_mfma_f32_16x16x32_bf16(af[mi], bf[nj], acc[mi][nj], 0, 0, 0);
    __syncthreads();   // drains prefetch (vmcnt 0) + protects both buffers
    cur ^= 1;
  }
  float* Pc = (EPI == EPI_PART) ? parts.p[blockIdx.z] : nullptr;
#pragma unroll
  for (int mi = 0; mi < 4; mi++) {
    const int rowb = bm + wm + mi * 16 + quad * 4;
#pragma unroll
    for (int nj = 0; nj < NF; nj++) {
      const int gn = bn + wn + nj * 16 + lr;
#pragma unroll
      for (int r = 0; r < 4; r++) {
        const size_t idx = (size_t)(rowb + r) * N + gn;
        float v = acc[mi][nj][r];
        if constexpr (EPI == EPI_BF16) {
          ((u16*)Cout)[idx] = f2bf(v);
        } else if constexpr (EPI == EPI_BIAS_RES) {
          ((float*)Cout)[idx] = v + bias[gn] + res[idx];
        } else if constexpr (EPI == EPI_BIAS_GELU) {
          float xg = v + bias[gn];
          ((u16*)Cout)[idx] = f2bf(0.5f * xg * (1.0f + erff(xg * 0.70710678118f)));
        } else if constexpr (EPI == EPI_BIAS_POS) {  // conv epilogue, N==768
          ((float*)Cout)[idx] = v + bias[gn] + res[(size_t)((rowb + r) & 1023) * N + gn];
        } else {  // EPI_PART: fp32 partial, combined later by redln_kernel
          Pc[idx] = v;
        }
      }
    }
  }
}

// ---------------- V transpose: qkvb v-cols [4096][2304] -> vT [48][64][1024] ----------------
__global__ __launch_bounds__(256) void vtr_kernel(const u16* __restrict__ qkvb,
                                                  u16* __restrict__ vT) {
  __shared__ uint32_t tile[64][65];
  const int t = threadIdx.x;
  const int bh = blockIdx.y, b = bh / 12, h = bh % 12;
  const int tok0 = blockIdx.x * 64;
  {
    int trow = t >> 2, dc = (t & 3) * 16;
    const u16* src = qkvb + (size_t)(b * 1024 + tok0 + trow) * 2304 + 1536 + h * 64 + dc;
    short8 v0 = *(const short8*)src;
    short8 v1 = *(const short8*)(src + 8);
#pragma unroll
    for (int j = 0; j < 8; j++) {
      tile[trow][dc + j] = (uint32_t)(u16)v0[j];
      tile[trow][dc + 8 + j] = (uint32_t)(u16)v1[j];
    }
  }
  __syncthreads();
  {
    int d = t >> 2, tc = (t & 3) * 16;
    short8 o0, o1;
#pragma unroll
    for (int j = 0; j < 8; j++) {
      o0[j] = (short)(u16)tile[tc + j][d];
      o1[j] = (short)(u16)tile[tc + 8 + j][d];
    }
    u16* dst = vT + (size_t)(bh * 64 + d) * 1024 + tok0 + tc;
    *(short8*)dst = o0;
    *(short8*)(dst + 8) = o1;
  }
}

// ---------------- flash attention, S^T formulation, v2 ----------------
// (unchanged — verified: 4 waves, double-buffer, swizzled K/V)
__global__ __launch_bounds__(256, 3) void attn_kernel(const u16* __restrict__ qkv,
                                                      const u16* __restrict__ vT,
                                                      u16* __restrict__ o) {
  __shared__ __align__(16) u16 Ks[2][2 * 64 * 32];   // [buf][ks][key][32]
  __shared__ __align__(16) u16 Vs[2][2 * 64 * 32];   // [buf][ks][d][32]
  __shared__ __align__(16) u16 Ps[4][16 * 72];       // per-wave P [qlocal][key], pad 72
  const int t = threadIdx.x;
  const int w = t >> 6, l = t & 63, lr = l & 15, quad = l >> 4;
  const int bh = blockIdx.y, b = bh / 12, h = bh % 12;
  const int qb = blockIdx.x * 64 + w * 16;           // 16 q-rows per wave
  const int swz = (lr >> 1) & 3;                     // read-side column xor

  short8 aq[2];
#pragma unroll
  for (int ks = 0; ks < 2; ks++)
    aq[ks] = *(const short8*)(qkv + (size_t)(b * 1024 + qb + lr) * 2304 +
                              h * 64 + ks * 32 + quad * 8);

  const u16* kbase = qkv + (size_t)(b * 1024) * 2304 + 768 + h * 64;
  const u16* vbase = vT + (size_t)(bh * 64) * 1024;
  u16* Pw = Ps[w];

  f32x4 accO[4];
  float l_loc = 0.f;
#pragma unroll
  for (int dj = 0; dj < 4; dj++) accO[dj] = (f32x4){0.f, 0.f, 0.f, 0.f};

  auto stage = [&](int buf, int kb) {
#pragma unroll
    for (int pass = 0; pass < 2; pass++) {
      int u = pass * 256 + t;                  // 16B unit, 0..511
      int ks = u >> 8, row = (u >> 2) & 63, c4 = u & 3;
      int cs = c4 ^ ((row >> 1) & 3);          // pre-swizzled source column
      g2l16(kbase + (size_t)(kb + row) * 2304 + ks * 32 + cs * 8, Ks[buf] + (size_t)u * 8);
      g2l16(vbase + (size_t)row * 1024 + kb + ks * 32 + cs * 8, Vs[buf] + (size_t)u * 8);
    }
  };

  stage(0, 0);
  __syncthreads();
  int cur = 0;
  for (int kb = 0; kb < 1024; kb += 64) {
    if (kb + 64 < 1024) stage(cur ^ 1, kb + 64);   // prefetch next tile

    f32x4 s[4];
#pragma unroll
    for (int nj = 0; nj < 4; nj++) s[nj] = (f32x4){0.f, 0.f, 0.f, 0.f};
#pragma unroll
    for (int ks = 0; ks < 2; ks++)
#pragma unroll
      for (int nj = 0; nj < 4; nj++) {
        short8 ak = *(const short8*)(Ks[cur] + ks * 2048 + (nj * 16 + lr) * 32 + (quad ^ swz) * 8);
        s[nj] = __builtin_amdgcn_mfma_f32_16x16x32_bf16(ak, aq[ks], s[nj], 0, 0, 0);
      }

    {
      const int rowoff = lr * 72;
#pragma unroll
      for (int nj = 0; nj < 4; nj++) {
        s16x4 pk;
#pragma unroll
        for (int r = 0; r < 4; r++) {
          float p = exp2f(s[nj][r] * 0.18033688011112042f);
          l_loc += p;
          pk[r] = (short)f2bf(p);
        }
        *(s16x4*)(Pw + rowoff + nj * 16 + quad * 4) = pk;
      }
    }

#pragma unroll
    for (int ks = 0; ks < 2; ks++) {
      short8 bp = *(const short8*)(Pw + lr * 72 + ks * 32 + quad * 8);
#pragma unroll
      for (int dj = 0; dj < 4; dj++) {
        short8 av = *(const short8*)(Vs[cur] + ks * 2048 + (dj * 16 + lr) * 32 + (quad ^ swz) * 8);
        accO[dj] = __builtin_amdgcn_mfma_f32_16x16x32_bf16(av, bp, accO[dj], 0, 0, 0);
      }
    }
    __syncthreads();
    cur ^= 1;
  }

  l_loc += __shfl_xor(l_loc, 16);
  l_loc += __shfl_xor(l_loc, 32);
  {
    float inv = 1.0f / l_loc;
    size_t grow = (size_t)(b * 1024 + qb + lr);
#pragma unroll
    for (int dj = 0; dj < 4; dj++) {
      s16x4 ov;
#pragma unroll
      for (int r = 0; r < 4; r++) ov[r] = (short)f2bf(accO[dj][r] * inv);
      *(s16x4*)(o + grow * 768 + h * 64 + dj * 16 + quad * 4) = ov;
    }
  }
}

// ---------------- driver ----------------
extern "C" void kernel_launch(void* const* d_in, const int* in_sizes, int n_in,
                              void* d_out, int out_size, void* d_ws, size_t ws_size,
                              hipStream_t stream) {
  (void)in_sizes; (void)n_in; (void)out_size; (void)ws_size;
  const float* c_f    = (const float*)d_in[0];
  const float* conv_w = (const float*)d_in[1];
  const float* conv_b = (const float*)d_in[2];
  const float* ln1_w  = (const float*)d_in[3];
  const float* ln1_b  = (const float*)d_in[4];
  const float* qkv_w  = (const float*)d_in[5];
  const float* out_w  = (const float*)d_in[6];
  const float* out_b  = (const float*)d_in[7];
  const float* ln2_w  = (const float*)d_in[8];
  const float* ln2_b  = (const float*)d_in[9];
  const float* m1w    = (const float*)d_in[10];
  const float* m1b    = (const float*)d_in[11];
  const float* m2w    = (const float*)d_in[12];
  const float* m2b    = (const float*)d_in[13];
  float* out = (float*)d_out;

  // Memory layout (R6-verified):
  //   x | y | qkvb | ob | hb | aconv | convw | wqkv | wout | wm1 | pos | wm2
  // mlp2 split-K=4 partials (12.58M each), live mlp2(l) -> redln-ln1(l+1):
  //   pm0 = qkvb[0..12.58M), pm1 = qkvb[12.58M..)+ob, pm2 = d_out,
  //   pm3 = aconv..wm1 + head of pos (redln runs BEFORE wconv of next layer)
  const size_t PSZ = 4096ull * 768 * 4;                 // 12,582,912

  char* p = (char*)d_ws;
  auto alloc = [&](size_t bytes) { char* q = p; p += (bytes + 255) & ~(size_t)255; return q; };
  float* x    = (float*)alloc(4096ull * 768 * 4);
  u16* y      = (u16*)alloc(4096ull * 768 * 2);
  u16* qkvb   = (u16*)alloc(4096ull * 2304 * 2);
  u16* ob     = (u16*)alloc(4096ull * 768 * 2);
  u16* hb     = (u16*)alloc(4096ull * 3072 * 2);
  u16* aconv  = (u16*)alloc(4096ull * 256 * 2);
  u16* convw  = (u16*)alloc(768ull * 256 * 2);
  u16* wqkv   = (u16*)alloc(2304ull * 768 * 2);
  u16* wout   = (u16*)alloc(768ull * 768 * 2);
  u16* wm1    = (u16*)alloc(3072ull * 768 * 2);
  float* pos  = (float*)alloc(1024ull * 768 * 4);       // dead after conv epilogue
  u16* wm2    = (u16*)alloc(768ull * 3072 * 2);
  // vT [48][64][1024] bf16 (6.3 MB) aliases hb (25 MB): hb dead during attn.
  u16* vT = hb;

  P4 pm{};   // mlp2 partials (split-K=4)
  pm.p[0] = (float*)qkvb;
  pm.p[1] = (float*)((char*)qkvb + PSZ);
  pm.p[2] = (float*)out;
  pm.p[3] = (float*)aconv;     // aconv..wm1 (11.93M) + head of pos (0.65M)
  P4 none{};

  pos_kernel<<<1024, 256, 0, stream>>>(pos);
  convw_kernel<<<768, 256, 0, stream>>>(conv_w, convw);
  cf_tr_kernel<<<dim3(32, 8, 4), 256, 0, stream>>>(c_f, aconv);
  gemm_bt<EPI_BIAS_POS, 64><<<dim3(12, 32), 256, 0, stream>>>(aconv, convw, conv_b, pos, x, 4096, 768, 256, none);

  for (int lyr = 0; lyr < 8; lyr++) {
    // redln FIRST (reads mlp2 partials incl. the weight region), THEN wconv
    if (lyr == 0) {
      ln_kernel<<<4096, 256, 0, stream>>>(x, ln1_w, ln1_b, y);
    } else {
      redln_kernel<4, true><<<4096, 256, 0, stream>>>(pm, x, m2b + (lyr - 1) * 768,
                                                      ln1_w + lyr * 768, ln1_b + lyr * 768, x, y);
    }
    wconv_kernel<<<6912, 256, 0, stream>>>(qkv_w, out_w, m1w, m2w, wqkv, wout, wm1, wm2, lyr);
    gemm_bt<EPI_BF16><<<dim3(18, 32), 256, 0, stream>>>(y, wqkv, nullptr, nullptr, qkvb, 4096, 2304, 768, none);
    vtr_kernel<<<dim3(16, 48), 256, 0, stream>>>(qkvb, vT);
    attn_kernel<<<dim3(16, 48), 256, 0, stream>>>(qkvb, vT, ob);
    // out-proj: BN=64 tile -> 384 blocks, fused bias+residual epilogue
    gemm_bt<EPI_BIAS_RES, 64><<<dim3(12, 32), 256, 0, stream>>>(ob, wout, out_b + lyr * 768, x, x, 4096, 768, 768, none);
    ln_kernel<<<4096, 256, 0, stream>>>(x, ln2_w + lyr * 768, ln2_b + lyr * 768, y);
    gemm_bt<EPI_BIAS_GELU><<<dim3(24, 32), 256, 0, stream>>>(y, wm1, m1b + lyr * 3072, nullptr, hb, 4096, 3072, 768, none);
    // mlp2: split-K=4 into fp32 partials (768 blocks -> 3 blocks/CU)
    gemm_bt<EPI_PART><<<dim3(6, 32, 4), 256, 0, stream>>>(hb, wm2, nullptr, nullptr, nullptr, 4096, 768, 3072, pm);
  }
  // final combine (no LN needed; consumer is the output transpose)
  redln_kernel<4, false><<<4096, 256, 0, stream>>>(pm, x, m2b + 7 * 768, nullptr, nullptr, x, nullptr);
  out_tr_kernel<<<dim3(24, 32, 4), 256, 0, stream>>>(x, out);
}